// Round 6
// baseline (3441.866 us; speedup 1.0000x reference)
//
#include <hip/hip_runtime.h>
#include <hip/hip_bf16.h>
#include <math.h>

#define B_ 8
#define H_ 8
#define T_ 8192
#define D_ 64
#define NC_ 128
#define WSZ_ 64
#define T2_ (2*T_)
#define BH_ (B_*H_)
#define CAP_ 16

// workspace layout (bytes)
#define OFF_AUX    0
#define OFF_DEN    4096                              // den (fallback) / cnt (so-path), BH*T*4
#define OFF_QIDX   (OFF_DEN  + BH_*T_*4)
#define OFF_KIDX   (OFF_QIDX + BH_*NC_*WSZ_*4)
#define OFF_MEANST (OFF_KIDX + BH_*NC_*WSZ_*4)
#define OFF_DISTS  (OFF_MEANST + H_*NC_*D_*4)
// dists region: nbh*NC_*T2_*4 bytes; reused after topk as:
//   so      (bf16): BH*NC*WSZ*D*2 = 67.1 MB
//   entries (int) : BH*T*CAP*4    = 32   MB
#define SO_BYTES      ((size_t)BH_*NC_*WSZ_*D_*2)
#define ENTRIES_BYTES ((size_t)BH_*T_*CAP_*4)

__device__ __forceinline__ unsigned short f2bf(float f) {
    union { __hip_bfloat16 b; unsigned short s; } cv;
    cv.b = __float2bfloat16(f);
    return cv.s;
}
__device__ __forceinline__ float bf2f(unsigned short s) {
    return __uint_as_float(((unsigned)s) << 16);
}

// ---------------------------------------------------------------------------
// K0: transpose means [h][c][d] -> meanst [h][d][c]
// ---------------------------------------------------------------------------
__global__ __launch_bounds__(256)
void k_meanst(const float* __restrict__ means, float* __restrict__ meanst)
{
    int gid = blockIdx.x * 256 + threadIdx.x;
    int h = gid >> 13;
    int rem = gid & 8191;
    int d = rem >> 7;
    int c = rem & 127;
    meanst[gid] = means[((h << 7) | c) * 64 + d];
}

// ---------------------------------------------------------------------------
// K1 v4: dists + argmax + aux. 8tok x 8clu register tile with double-buffered
// register prefetch of means (2 d-steps ahead). FMA order per acc element is
// unchanged (ascending d) -> bitwise-identical dists vs prior rounds.
// grid: (T2/128, nbh)  block: 256
// ---------------------------------------------------------------------------
__global__ __launch_bounds__(256, 4)
void k_dists(const float* __restrict__ q, const float* __restrict__ k,
             const float* __restrict__ means, const float* __restrict__ meanst,
             float* __restrict__ dists, float* __restrict__ aux, int bh_base)
{
    __shared__ float xs[64 * 132];   // [d][token], stride 132
    __shared__ int   bcs[128];
    __shared__ float ar[4];

    const int tid = threadIdx.x;
    const int bhl = blockIdx.y;
    const int bh  = bh_base + bhl;
    const int h   = bh % H_;
    const int t0  = blockIdx.x * 128;

    // ---- phase 1: load 128 token rows, normalize, store transposed
    const int lane = tid & 63;
    const int w    = tid >> 6;
    for (int it = 0; it < 32; ++it) {
        int tl = it * 4 + w;
        int gt = t0 + tl;
        const float* src = (gt < T_)
            ? (q + ((size_t)bh * T_ + gt) * D_)
            : (k + ((size_t)bh * T_ + (gt - T_)) * D_);
        float vv = src[lane];
        float s = vv * vv;
        #pragma unroll
        for (int off = 32; off > 0; off >>= 1) s += __shfl_xor(s, off);
        float norm = fmaxf(sqrtf(s), 1e-12f);
        xs[lane * 132 + tl] = vv / norm;
    }
    __syncthreads();

    // ---- phase 2: 8x8 tile, means double-buffer prefetch (2 d per group)
    const int ty = tid >> 4;
    const int tx = tid & 15;
    float acc[8][8];
    #pragma unroll
    for (int i = 0; i < 8; ++i)
        #pragma unroll
        for (int j = 0; j < 8; ++j) acc[i][j] = 0.f;

    const float* mt = meanst + (size_t)h * (64 * 128) + tx * 8;

    float4 mA0, mA1, mA2, mA3, mB0, mB1, mB2, mB3;
    // preload group 0 (d=0,1)
    mA0 = *(const float4*)(mt + 0);
    mA1 = *(const float4*)(mt + 4);
    mA2 = *(const float4*)(mt + 128);
    mA3 = *(const float4*)(mt + 132);

#define CDOT(dd, M0, M1) { \
    float4 xa_ = *(const float4*)&xs[(dd) * 132 + ty * 8]; \
    float4 xb_ = *(const float4*)&xs[(dd) * 132 + ty * 8 + 4]; \
    float xv_[8] = {xa_.x, xa_.y, xa_.z, xa_.w, xb_.x, xb_.y, xb_.z, xb_.w}; \
    float mv_[8] = {M0.x, M0.y, M0.z, M0.w, M1.x, M1.y, M1.z, M1.w}; \
    _Pragma("unroll") \
    for (int i_ = 0; i_ < 8; ++i_) \
        _Pragma("unroll") \
        for (int j_ = 0; j_ < 8; ++j_) \
            acc[i_][j_] = fmaf(xv_[i_], mv_[j_], acc[i_][j_]); }

    for (int g = 0; g < 32; g += 2) {
        // prefetch group g+1 into B
        {
            int gn = (g + 1 < 32) ? g + 1 : 31;
            const float* p = mt + gn * 256;
            mB0 = *(const float4*)(p + 0);
            mB1 = *(const float4*)(p + 4);
            mB2 = *(const float4*)(p + 128);
            mB3 = *(const float4*)(p + 132);
        }
        // compute group g from A (d = 2g, 2g+1)
        CDOT(2 * g,     mA0, mA1);
        CDOT(2 * g + 1, mA2, mA3);
        // prefetch group g+2 into A
        {
            int gn = (g + 2 < 32) ? g + 2 : 31;
            const float* p = mt + gn * 256;
            mA0 = *(const float4*)(p + 0);
            mA1 = *(const float4*)(p + 4);
            mA2 = *(const float4*)(p + 128);
            mA3 = *(const float4*)(p + 132);
        }
        // compute group g+1 from B
        CDOT(2 * g + 2, mB0, mB1);
        CDOT(2 * g + 3, mB2, mB3);
    }
#undef CDOT

    // ---- phase 3: direct transposed global store
    #pragma unroll
    for (int j = 0; j < 8; ++j) {
        const int c = tx * 8 + j;
        float* gp = dists + ((size_t)(bhl * NC_ + c)) * T2_ + t0 + ty * 8;
        *(float4*)gp       = make_float4(acc[0][j], acc[1][j], acc[2][j], acc[3][j]);
        *(float4*)(gp + 4) = make_float4(acc[4][j], acc[5][j], acc[6][j], acc[7][j]);
    }

    // ---- phase 4: argmax across clusters
    #pragma unroll
    for (int i = 0; i < 8; ++i) {
        float bv = -1e30f; int bcid = 0;
        #pragma unroll
        for (int j = 0; j < 8; ++j) {
            float vv = acc[i][j];
            if (vv > bv) { bv = vv; bcid = tx * 8 + j; }
        }
        #pragma unroll
        for (int off = 1; off < 16; off <<= 1) {
            float ov = __shfl_xor(bv, off);
            int   oc = __shfl_xor(bcid, off);
            if (ov > bv || (ov == bv && oc < bcid)) { bv = ov; bcid = oc; }
        }
        if (tx == 0) bcs[ty * 8 + i] = bcid;
    }
    __syncthreads();

    // ---- phase 5: aux = sum (xn - mean_best)^2
    float part = 0.f;
    for (int it = 0; it < 32; ++it) {
        int tl = it * 4 + w;
        int cb = bcs[tl];
        const float* mr = means + ((size_t)(h * NC_ + cb)) * 64;
        float df = xs[lane * 132 + tl] - mr[lane];
        part = fmaf(df, df, part);
    }
    #pragma unroll
    for (int off = 32; off > 0; off >>= 1) part += __shfl_xor(part, off);
    if (lane == 0) ar[w] = part;
    __syncthreads();
    if (tid == 0) atomicAdd(aux, ar[0] + ar[1] + ar[2] + ar[3]);
}

// ---------------------------------------------------------------------------
// K2: top-64 of 8192 — register-resident, 12-bit histogram, parallel
// suffix-scan threshold, exact candidate rank.  (unchanged, passing)
// ---------------------------------------------------------------------------
__device__ __forceinline__ unsigned flip_f32(float f) {
    unsigned bits = __float_as_uint(f);
    return (bits & 0x80000000u) ? ~bits : (bits | 0x80000000u);
}

__global__ __launch_bounds__(256)
void k_topk(const float* __restrict__ dists, int* __restrict__ qidx,
            int* __restrict__ kidx, int bh_base)
{
    __shared__ unsigned hist[4096];
    __shared__ unsigned sfx[256];
    __shared__ unsigned wtot[4];
    __shared__ unsigned cand_u[768];
    __shared__ int      cand_i[768];
    __shared__ int sh[6];

    const int tid   = threadIdx.x;
    const int c     = blockIdx.x;
    const int bhl   = blockIdx.y;
    const int which = blockIdx.z;
    const float* row = dists + ((size_t)(bhl * NC_ + c)) * T2_ + (size_t)which * T_;
    int* outp = (which ? kidx : qidx) + ((size_t)((bh_base + bhl) * NC_ + c)) * WSZ_;

    unsigned u[32];
    {
        const float4* r4 = (const float4*)row;
        #pragma unroll
        for (int it = 0; it < 8; ++it) {
            float4 f = r4[it * 256 + tid];
            u[it * 4 + 0] = flip_f32(f.x);
            u[it * 4 + 1] = flip_f32(f.y);
            u[it * 4 + 2] = flip_f32(f.z);
            u[it * 4 + 3] = flip_f32(f.w);
        }
    }
    for (int i = tid; i < 4096; i += 256) hist[i] = 0;
    if (tid < 6) sh[tid] = (tid < 2) ? -1 : 0;
    __syncthreads();

    #pragma unroll
    for (int j = 0; j < 32; ++j) atomicAdd(&hist[u[j] >> 20], 1u);
    __syncthreads();

    unsigned gs = 0;
    #pragma unroll
    for (int j = 0; j < 16; ++j) gs += hist[tid * 16 + j];

    const int l = tid & 63, w = tid >> 6;
    unsigned sv = gs;
    #pragma unroll
    for (int off = 1; off < 64; off <<= 1) {
        unsigned up = __shfl_down(sv, off);
        if (l + off < 64) sv += up;
    }
    if (l == 0) wtot[w] = sv;
    __syncthreads();
    unsigned hi = 0;
    for (int ww = w + 1; ww < 4; ++ww) hi += wtot[ww];
    unsigned suffix = sv + hi;
    sfx[tid] = suffix;
    if (suffix >= WSZ_) atomicMax(&sh[0], tid);
    __syncthreads();
    const int g1 = sh[0];
    const unsigned above_groups = (g1 < 255) ? sfx[g1 + 1] : 0u;

    if (tid < 16) {
        unsigned bs = above_groups;
        for (int j = 15; j >= tid; --j) bs += hist[g1 * 16 + j];
        if (bs >= WSZ_) atomicMax(&sh[1], g1 * 16 + tid);
    }
    __syncthreads();
    const int b1 = sh[1];
    if (tid == 0) {
        unsigned gt = above_groups;
        for (int j = b1 + 1; j <= g1 * 16 + 15; ++j) gt += hist[j];
        sh[4] = WSZ_ - (int)gt;
    }
    __syncthreads();
    const int kk = sh[4];

    #pragma unroll
    for (int j = 0; j < 32; ++j) {
        int bin = (int)(u[j] >> 20);
        int idx = (j >> 2) * 1024 + tid * 4 + (j & 3);
        if (bin > b1) {
            int p = atomicAdd(&sh[2], 1);
            outp[p] = idx;
        } else if (bin == b1) {
            int p = atomicAdd(&sh[3], 1);
            if (p < 768) { cand_u[p] = u[j]; cand_i[p] = idx; }
        }
    }
    __syncthreads();
    const int G = sh[2];
    const int C = sh[3];

    if (C <= 768) {
        for (int j = tid; j < C; j += 256) {
            unsigned uj = cand_u[j]; int ij = cand_i[j];
            int rank = 0;
            for (int ll = 0; ll < C; ++ll) {
                unsigned ul = cand_u[ll];
                rank += (int)((ul > uj) || (ul == uj && cand_i[ll] < ij));
            }
            if (rank < kk) outp[G + rank] = ij;
        }
        return;
    }

    // fallback: full 4-level radix re-reading global
    unsigned prefix = 0, mask = 0;
    int need = WSZ_;
    for (int shift = 24; shift >= 0; shift -= 8) {
        if (tid < 256) hist[tid] = 0;
        __syncthreads();
        for (int it = 0; it < 32; ++it) {
            unsigned uu = flip_f32(row[it * 256 + tid]);
            if ((uu & mask) == prefix) atomicAdd(&hist[(uu >> shift) & 255u], 1u);
        }
        __syncthreads();
        if (tid == 0) {
            int b = 255;
            int k2 = need;
            while (b > 0) {
                int cnt = (int)hist[b];
                if (k2 - cnt <= 0) break;
                k2 -= cnt; --b;
            }
            sh[0] = k2; sh[1] = b;
        }
        __syncthreads();
        need = sh[0];
        prefix |= ((unsigned)sh[1]) << shift;
        mask   |= 0xFFu << shift;
        __syncthreads();
    }
    if (tid == 0) { sh[2] = 0; sh[3] = 0; }
    __syncthreads();
    const unsigned thr = prefix;
    for (int it = 0; it < 32; ++it) {
        int i = it * 256 + tid;
        unsigned uu = flip_f32(row[i]);
        if (uu > thr) {
            int p = atomicAdd(&sh[2], 1);
            outp[p] = i;
        } else if (uu == thr) {
            int p = atomicAdd(&sh[3], 1);
            if (p < 768) cand_i[p] = i;
        }
    }
    __syncthreads();
    if (tid == 0) {
        int base = sh[2];
        int E = sh[3] < 768 ? sh[3] : 768;
        for (int n = 0; n < need; ++n) {
            int mi = 0x7fffffff, mj = 0;
            for (int j = 0; j < E; ++j) {
                int vv = cand_i[j];
                if (vv < mi) { mi = vv; mj = j; }
            }
            cand_i[mj] = 0x7fffffff;
            outp[base + n] = mi;
        }
    }
}

// ---------------------------------------------------------------------------
// K3-so v2: r4-proven attention body (padded-68 LDS, low VGPR) + so/entries
// gather epilogue. so rows written unconditionally (coalesced bf16); overflow
// beyond CAP also atomics into out (rare).
// grid: (NC, BH)  block: 256
// ---------------------------------------------------------------------------
__global__ __launch_bounds__(256, 4)
void k_attn_w(const float* __restrict__ q, const float* __restrict__ k,
              const float* __restrict__ v, const int* __restrict__ qidx,
              const int* __restrict__ kidx, unsigned short* __restrict__ so,
              int* __restrict__ cnt, int* __restrict__ entries,
              float* __restrict__ out)
{
    __shared__ float As[64 * 68];   // Q, then P
    __shared__ float Bs[64 * 68];   // K, then V
    __shared__ int qi[64], ki[64], lp[64];

    const int tid = threadIdx.x;
    const int c  = blockIdx.x;
    const int bh = blockIdx.y;
    const int* qp = qidx + ((size_t)(bh * NC_ + c)) * WSZ_;
    const int* kp = kidx + ((size_t)(bh * NC_ + c)) * WSZ_;
    if (tid < 64) { qi[tid] = qp[tid]; ki[tid] = kp[tid]; }
    __syncthreads();

    const int grow = tid >> 2, gseg = (tid & 3) * 16;
    {
        const float* qsrc = q + ((size_t)bh * T_ + qi[grow]) * D_ + gseg;
        const float* ksrc = k + ((size_t)bh * T_ + ki[grow]) * D_ + gseg;
        #pragma unroll
        for (int j4 = 0; j4 < 4; ++j4) {
            *(float4*)&As[grow * 68 + gseg + j4 * 4] = ((const float4*)qsrc)[j4];
            *(float4*)&Bs[grow * 68 + gseg + j4 * 4] = ((const float4*)ksrc)[j4];
        }
    }
    __syncthreads();

    const int tx = tid & 15;
    const int ty = tid >> 4;

    float sacc[4][4];
    #pragma unroll
    for (int i = 0; i < 4; ++i)
        #pragma unroll
        for (int j = 0; j < 4; ++j) sacc[i][j] = 0.f;

    for (int kk4 = 0; kk4 < 16; ++kk4) {
        float4 qv[4], kv[4];
        #pragma unroll
        for (int i = 0; i < 4; ++i) qv[i] = *(const float4*)&As[(ty * 4 + i) * 68 + kk4 * 4];
        #pragma unroll
        for (int j = 0; j < 4; ++j) kv[j] = *(const float4*)&Bs[(tx * 4 + j) * 68 + kk4 * 4];
        #pragma unroll
        for (int i = 0; i < 4; ++i)
            #pragma unroll
            for (int j = 0; j < 4; ++j)
                sacc[i][j] = fmaf(qv[i].w, kv[j].w, fmaf(qv[i].z, kv[j].z,
                              fmaf(qv[i].y, kv[j].y, fmaf(qv[i].x, kv[j].x, sacc[i][j]))));
    }
    __syncthreads();

    {
        const float* vsrc = v + ((size_t)bh * T_ + ki[grow]) * D_ + gseg;
        #pragma unroll
        for (int j4 = 0; j4 < 4; ++j4)
            *(float4*)&Bs[grow * 68 + gseg + j4 * 4] = ((const float4*)vsrc)[j4];
    }

    float rinv[4];
    #pragma unroll
    for (int i = 0; i < 4; ++i) {
        float m = fmaxf(fmaxf(sacc[i][0], sacc[i][1]), fmaxf(sacc[i][2], sacc[i][3]));
        m = fmaxf(m, __shfl_xor(m, 1));
        m = fmaxf(m, __shfl_xor(m, 2));
        m = fmaxf(m, __shfl_xor(m, 4));
        m = fmaxf(m, __shfl_xor(m, 8));
        float4 ev;
        ev.x = expf((sacc[i][0] - m) * 0.125f);
        ev.y = expf((sacc[i][1] - m) * 0.125f);
        ev.z = expf((sacc[i][2] - m) * 0.125f);
        ev.w = expf((sacc[i][3] - m) * 0.125f);
        float s = ev.x + ev.y + ev.z + ev.w;
        s += __shfl_xor(s, 1);
        s += __shfl_xor(s, 2);
        s += __shfl_xor(s, 4);
        s += __shfl_xor(s, 8);
        rinv[i] = 1.0f / s;
        *(float4*)&As[(ty * 4 + i) * 68 + tx * 4] = ev;
    }
    __syncthreads();

    float oacc[4][4];
    #pragma unroll
    for (int i = 0; i < 4; ++i)
        #pragma unroll
        for (int j = 0; j < 4; ++j) oacc[i][j] = 0.f;

    for (int jj4 = 0; jj4 < 16; ++jj4) {
        float4 vv[4];
        #pragma unroll
        for (int ll = 0; ll < 4; ++ll) vv[ll] = *(const float4*)&Bs[(jj4 * 4 + ll) * 68 + tx * 4];
        #pragma unroll
        for (int i = 0; i < 4; ++i) {
            float4 pv = *(const float4*)&As[(ty * 4 + i) * 68 + jj4 * 4];
            oacc[i][0] = fmaf(pv.w, vv[3].x, fmaf(pv.z, vv[2].x, fmaf(pv.y, vv[1].x, fmaf(pv.x, vv[0].x, oacc[i][0]))));
            oacc[i][1] = fmaf(pv.w, vv[3].y, fmaf(pv.z, vv[2].y, fmaf(pv.y, vv[1].y, fmaf(pv.x, vv[0].y, oacc[i][1]))));
            oacc[i][2] = fmaf(pv.w, vv[3].z, fmaf(pv.z, vv[2].z, fmaf(pv.y, vv[1].z, fmaf(pv.x, vv[0].z, oacc[i][2]))));
            oacc[i][3] = fmaf(pv.w, vv[3].w, fmaf(pv.z, vv[2].w, fmaf(pv.y, vv[1].w, fmaf(pv.x, vv[0].w, oacc[i][3]))));
        }
    }

    // ---- registration: one thread per row claims an inverse-list slot
    if (tx == 0) {
        #pragma unroll
        for (int i = 0; i < 4; ++i) {
            int r = ty * 4 + i;
            int t = qi[r];
            int p = atomicAdd(&cnt[(size_t)bh * T_ + t], 1);
            if (p < CAP_) entries[((size_t)bh * T_ + t) * CAP_ + p] = c * WSZ_ + r;
            lp[r] = p;
        }
    }
    __syncthreads();

    // ---- emit so rows (always); overflow rows also atomic into out (rare)
    #pragma unroll
    for (int i = 0; i < 4; ++i) {
        const int r = ty * 4 + i;
        float o0 = oacc[i][0] * rinv[i];
        float o1 = oacc[i][1] * rinv[i];
        float o2 = oacc[i][2] * rinv[i];
        float o3 = oacc[i][3] * rinv[i];
        unsigned short* dst = so + (((size_t)(bh * NC_ + c)) * WSZ_ + r) * D_ + tx * 4;
        union { unsigned short s[4]; uint2 v; } pk;
        pk.s[0] = f2bf(o0); pk.s[1] = f2bf(o1);
        pk.s[2] = f2bf(o2); pk.s[3] = f2bf(o3);
        *(uint2*)dst = pk.v;
        if (lp[r] >= CAP_) {
            float* ob = out + ((size_t)bh * T_ + qi[r]) * D_ + tx * 4;
            atomicAdd(ob + 0, o0); atomicAdd(ob + 1, o1);
            atomicAdd(ob + 2, o2); atomicAdd(ob + 3, o3);
        }
    }
}

// ---------------------------------------------------------------------------
// K4-so: gather finalize: out[t] = (sum of registered so rows + overflow)/(n+eps)
// grid: (T/16, BH)  block: 256
// ---------------------------------------------------------------------------
__global__ __launch_bounds__(256)
void k_gather(const unsigned short* __restrict__ so, const int* __restrict__ cnt,
              const int* __restrict__ entries, float* __restrict__ out,
              const float* __restrict__ aux)
{
    const int tid = threadIdx.x;
    const int tk  = blockIdx.x * 16 + (tid >> 4);
    const int bh  = blockIdx.y;
    const int d4  = (tid & 15) * 4;
    const size_t tix = (size_t)bh * T_ + tk;

    const int n = cnt[tix];
    const int m = n < CAP_ ? n : CAP_;
    const int* ep = entries + tix * CAP_;

    float a0 = 0.f, a1 = 0.f, a2 = 0.f, a3 = 0.f;
    for (int j = 0; j < m; ++j) {
        int e = ep[j];
        const unsigned short* sp = so + ((size_t)bh * (NC_ * WSZ_) + e) * D_ + d4;
        uint2 raw = *(const uint2*)sp;
        a0 += bf2f((unsigned short)(raw.x & 0xffffu));
        a1 += bf2f((unsigned short)(raw.x >> 16));
        a2 += bf2f((unsigned short)(raw.y & 0xffffu));
        a3 += bf2f((unsigned short)(raw.y >> 16));
    }
    float* op = out + tix * D_ + d4;
    float4 pr = *(float4*)op;                 // overflow base (normally 0)
    float inv = 1.0f / ((float)n + 1e-5f);
    float4 r;
    r.x = (a0 + pr.x) * inv;
    r.y = (a1 + pr.y) * inv;
    r.z = (a2 + pr.z) * inv;
    r.w = (a3 + pr.w) * inv;
    *(float4*)op = r;

    if (blockIdx.x == 0 && bh == 0 && tid == 0)
        out[(size_t)BH_ * T_ * D_] = aux[0] * 1.4901161193847656e-12f;
}

// ---------------------------------------------------------------------------
// K3/K4 fallback (small-ws): exact atomic-scatter path
// ---------------------------------------------------------------------------
__global__ __launch_bounds__(256)
void k_attn(const float* __restrict__ q, const float* __restrict__ k,
            const float* __restrict__ v, const int* __restrict__ qidx,
            const int* __restrict__ kidx, float* __restrict__ out,
            float* __restrict__ den)
{
    __shared__ float As[64 * 68];
    __shared__ float Bs[64 * 68];
    __shared__ int qi[64], ki[64];

    const int tid = threadIdx.x;
    const int c  = blockIdx.x;
    const int bh = blockIdx.y;
    const int* qp = qidx + ((size_t)(bh * NC_ + c)) * WSZ_;
    const int* kp = kidx + ((size_t)(bh * NC_ + c)) * WSZ_;
    if (tid < 64) { qi[tid] = qp[tid]; ki[tid] = kp[tid]; }
    __syncthreads();

    const int grow = tid >> 2, gseg = (tid & 3) * 16;
    {
        const float* qsrc = q + ((size_t)bh * T_ + qi[grow]) * D_ + gseg;
        const float* ksrc = k + ((size_t)bh * T_ + ki[grow]) * D_ + gseg;
        #pragma unroll
        for (int j4 = 0; j4 < 4; ++j4) {
            *(float4*)&As[grow * 68 + gseg + j4 * 4] = ((const float4*)qsrc)[j4];
            *(float4*)&Bs[grow * 68 + gseg + j4 * 4] = ((const float4*)ksrc)[j4];
        }
    }
    __syncthreads();

    const int tx = tid & 15;
    const int ty = tid >> 4;

    float sacc[4][4];
    #pragma unroll
    for (int i = 0; i < 4; ++i)
        #pragma unroll
        for (int j = 0; j < 4; ++j) sacc[i][j] = 0.f;

    for (int kk4 = 0; kk4 < 16; ++kk4) {
        float4 qv[4], kv[4];
        #pragma unroll
        for (int i = 0; i < 4; ++i) qv[i] = *(const float4*)&As[(ty * 4 + i) * 68 + kk4 * 4];
        #pragma unroll
        for (int j = 0; j < 4; ++j) kv[j] = *(const float4*)&Bs[(tx * 4 + j) * 68 + kk4 * 4];
        #pragma unroll
        for (int i = 0; i < 4; ++i)
            #pragma unroll
            for (int j = 0; j < 4; ++j)
                sacc[i][j] = fmaf(qv[i].w, kv[j].w, fmaf(qv[i].z, kv[j].z,
                              fmaf(qv[i].y, kv[j].y, fmaf(qv[i].x, kv[j].x, sacc[i][j]))));
    }
    __syncthreads();

    {
        const float* vsrc = v + ((size_t)bh * T_ + ki[grow]) * D_ + gseg;
        #pragma unroll
        for (int j4 = 0; j4 < 4; ++j4)
            *(float4*)&Bs[grow * 68 + gseg + j4 * 4] = ((const float4*)vsrc)[j4];
    }

    float rinv[4];
    #pragma unroll
    for (int i = 0; i < 4; ++i) {
        float m = fmaxf(fmaxf(sacc[i][0], sacc[i][1]), fmaxf(sacc[i][2], sacc[i][3]));
        m = fmaxf(m, __shfl_xor(m, 1));
        m = fmaxf(m, __shfl_xor(m, 2));
        m = fmaxf(m, __shfl_xor(m, 4));
        m = fmaxf(m, __shfl_xor(m, 8));
        float4 ev;
        ev.x = expf((sacc[i][0] - m) * 0.125f);
        ev.y = expf((sacc[i][1] - m) * 0.125f);
        ev.z = expf((sacc[i][2] - m) * 0.125f);
        ev.w = expf((sacc[i][3] - m) * 0.125f);
        float s = ev.x + ev.y + ev.z + ev.w;
        s += __shfl_xor(s, 1);
        s += __shfl_xor(s, 2);
        s += __shfl_xor(s, 4);
        s += __shfl_xor(s, 8);
        rinv[i] = 1.0f / s;
        *(float4*)&As[(ty * 4 + i) * 68 + tx * 4] = ev;
    }
    __syncthreads();

    float oacc[4][4];
    #pragma unroll
    for (int i = 0; i < 4; ++i)
        #pragma unroll
        for (int j = 0; j < 4; ++j) oacc[i][j] = 0.f;

    for (int jj4 = 0; jj4 < 16; ++jj4) {
        float4 vv[4];
        #pragma unroll
        for (int ll = 0; ll < 4; ++ll) vv[ll] = *(const float4*)&Bs[(jj4 * 4 + ll) * 68 + tx * 4];
        #pragma unroll
        for (int i = 0; i < 4; ++i) {
            float4 pv = *(const float4*)&As[(ty * 4 + i) * 68 + jj4 * 4];
            oacc[i][0] = fmaf(pv.w, vv[3].x, fmaf(pv.z, vv[2].x, fmaf(pv.y, vv[1].x, fmaf(pv.x, vv[0].x, oacc[i][0]))));
            oacc[i][1] = fmaf(pv.w, vv[3].y, fmaf(pv.z, vv[2].y, fmaf(pv.y, vv[1].y, fmaf(pv.x, vv[0].y, oacc[i][1]))));
            oacc[i][2] = fmaf(pv.w, vv[3].z, fmaf(pv.z, vv[2].z, fmaf(pv.y, vv[1].z, fmaf(pv.x, vv[0].z, oacc[i][2]))));
            oacc[i][3] = fmaf(pv.w, vv[3].w, fmaf(pv.z, vv[2].w, fmaf(pv.y, vv[1].w, fmaf(pv.x, vv[0].w, oacc[i][3]))));
        }
    }

    #pragma unroll
    for (int i = 0; i < 4; ++i) {
        const int r = ty * 4 + i;
        float* obase = out + ((size_t)bh * T_ + qi[r]) * D_ + tx * 4;
        #pragma unroll
        for (int j = 0; j < 4; ++j) atomicAdd(obase + j, oacc[i][j] * rinv[i]);
    }
    if (tx == 0) {
        #pragma unroll
        for (int i = 0; i < 4; ++i) atomicAdd(den + (size_t)bh * T_ + qi[ty * 4 + i], 1.0f);
    }
}

__global__ __launch_bounds__(256)
void k_final(float* __restrict__ out, const float* __restrict__ den,
             const float* __restrict__ aux)
{
    size_t gid = (size_t)blockIdx.x * 256 + threadIdx.x;
    float4* o4 = (float4*)out;
    float d = den[gid >> 4] + 1e-5f;
    float4 x = o4[gid];
    x.x = x.x / d; x.y = x.y / d; x.z = x.z / d; x.w = x.w / d;
    o4[gid] = x;
    if (gid == 0) out[(size_t)BH_ * T_ * D_] = aux[0] * 1.4901161193847656e-12f;
}

extern "C" void kernel_launch(void* const* d_in, const int* in_sizes, int n_in,
                              void* d_out, int out_size, void* d_ws, size_t ws_size,
                              hipStream_t stream) {
    const float* q     = (const float*)d_in[0];
    const float* k     = (const float*)d_in[1];
    const float* v     = (const float*)d_in[2];
    const float* means = (const float*)d_in[3];
    float* out = (float*)d_out;
    char*  ws  = (char*)d_ws;
    float* aux    = (float*)(ws + OFF_AUX);
    float* den    = (float*)(ws + OFF_DEN);     // cnt (int) in so-path
    int*   qidx   = (int*)(ws + OFF_QIDX);
    int*   kidx   = (int*)(ws + OFF_KIDX);
    float* meanst = (float*)(ws + OFF_MEANST);
    float* dists  = (float*)(ws + OFF_DISTS);

    hipMemsetAsync(out, 0, (size_t)((size_t)BH_ * T_ * D_ + 1) * 4, stream);
    hipMemsetAsync(ws, 0, (size_t)OFF_QIDX, stream);   // aux + den/cnt

    k_meanst<<<256, 256, 0, stream>>>(means, meanst);

    size_t region = (ws_size > OFF_DISTS) ? ws_size - (size_t)OFF_DISTS : 0;
    size_t per_bh = (size_t)NC_ * T2_ * 4;   // 8 MB
    int nbh = (int)(region / per_bh);
    nbh = nbh < 1 ? 1 : (nbh > BH_ ? BH_ : nbh);
    const bool sopath = region >= (SO_BYTES + ENTRIES_BYTES);

    for (int bh_base = 0; bh_base < BH_; bh_base += nbh) {
        int cur = BH_ - bh_base < nbh ? BH_ - bh_base : nbh;
        k_dists<<<dim3(T2_ / 128, cur), 256, 0, stream>>>(q, k, means, meanst, dists, aux, bh_base);
        k_topk <<<dim3(NC_, cur, 2),    256, 0, stream>>>(dists, qidx, kidx, bh_base);
    }

    if (sopath) {
        unsigned short* so = (unsigned short*)(ws + OFF_DISTS);
        int* entries = (int*)(ws + OFF_DISTS + SO_BYTES);
        k_attn_w<<<dim3(NC_, BH_), 256, 0, stream>>>(q, k, v, qidx, kidx,
                                                     so, (int*)den, entries, out);
        k_gather<<<dim3(T_ / 16, BH_), 256, 0, stream>>>(so, (int*)den, entries, out, aux);
    } else {
        k_attn<<<dim3(NC_, BH_), 256, 0, stream>>>(q, k, v, qidx, kidx, out, den);
        k_final<<<(BH_ * T_ * D_ / 4 + 255) / 256, 256, 0, stream>>>(out, den, aux);
    }
}

// Round 7
// 1795.437 us; speedup vs baseline: 1.9170x; 1.9170x over previous
//
#include <hip/hip_runtime.h>
#include <hip/hip_bf16.h>
#include <math.h>

#define B_ 8
#define H_ 8
#define T_ 8192
#define D_ 64
#define NC_ 128
#define WSZ_ 64
#define T2_ (2*T_)
#define BH_ (B_*H_)
#define CAP_ 16

// workspace layout (bytes)
#define OFF_AUX    0
#define OFF_DEN    4096                              // den (fallback) / cnt (so-path), BH*T*4
#define OFF_QIDX   (OFF_DEN  + BH_*T_*4)
#define OFF_KIDX   (OFF_QIDX + BH_*NC_*WSZ_*4)
#define OFF_MEANST (OFF_KIDX + BH_*NC_*WSZ_*4)
#define OFF_DISTS  (OFF_MEANST + H_*NC_*D_*4)
// dists region: nbh*NC_*T2_*4 bytes; reused after topk as:
//   so      (bf16): BH*NC*WSZ*D*2 = 67.1 MB
//   entries (int) : BH*T*CAP*4    = 32   MB
#define SO_BYTES      ((size_t)BH_*NC_*WSZ_*D_*2)
#define ENTRIES_BYTES ((size_t)BH_*T_*CAP_*4)

__device__ __forceinline__ unsigned f2bf_u(float f) {
    union { __hip_bfloat16 b; unsigned short s; } cv;
    cv.b = __float2bfloat16(f);
    return (unsigned)cv.s;
}
__device__ __forceinline__ float bf2f(unsigned short s) {
    return __uint_as_float(((unsigned)s) << 16);
}

// ---------------------------------------------------------------------------
// K0: transpose means [h][c][d] -> meanst [h][d][c]
// ---------------------------------------------------------------------------
__global__ __launch_bounds__(256)
void k_meanst(const float* __restrict__ means, float* __restrict__ meanst)
{
    int gid = blockIdx.x * 256 + threadIdx.x;
    int h = gid >> 13;
    int rem = gid & 8191;
    int d = rem >> 7;
    int c = rem & 127;
    meanst[gid] = means[((h << 7) | c) * 64 + d];
}

// ---------------------------------------------------------------------------
// K1 v4: dists + argmax + aux. 8tok x 8clu register tile with double-buffered
// register prefetch of means. FMA order per acc element unchanged (ascending
// d) -> bitwise-identical dists vs prior rounds.
// grid: (T2/128, nbh)  block: 256
// ---------------------------------------------------------------------------
__global__ __launch_bounds__(256, 4)
void k_dists(const float* __restrict__ q, const float* __restrict__ k,
             const float* __restrict__ means, const float* __restrict__ meanst,
             float* __restrict__ dists, float* __restrict__ aux, int bh_base)
{
    __shared__ float xs[64 * 132];   // [d][token], stride 132
    __shared__ int   bcs[128];
    __shared__ float ar[4];

    const int tid = threadIdx.x;
    const int bhl = blockIdx.y;
    const int bh  = bh_base + bhl;
    const int h   = bh % H_;
    const int t0  = blockIdx.x * 128;

    const int lane = tid & 63;
    const int w    = tid >> 6;
    for (int it = 0; it < 32; ++it) {
        int tl = it * 4 + w;
        int gt = t0 + tl;
        const float* src = (gt < T_)
            ? (q + ((size_t)bh * T_ + gt) * D_)
            : (k + ((size_t)bh * T_ + (gt - T_)) * D_);
        float vv = src[lane];
        float s = vv * vv;
        #pragma unroll
        for (int off = 32; off > 0; off >>= 1) s += __shfl_xor(s, off);
        float norm = fmaxf(sqrtf(s), 1e-12f);
        xs[lane * 132 + tl] = vv / norm;
    }
    __syncthreads();

    const int ty = tid >> 4;
    const int tx = tid & 15;
    float acc[8][8];
    #pragma unroll
    for (int i = 0; i < 8; ++i)
        #pragma unroll
        for (int j = 0; j < 8; ++j) acc[i][j] = 0.f;

    const float* mt = meanst + (size_t)h * (64 * 128) + tx * 8;

    float4 mA0, mA1, mA2, mA3, mB0, mB1, mB2, mB3;
    mA0 = *(const float4*)(mt + 0);
    mA1 = *(const float4*)(mt + 4);
    mA2 = *(const float4*)(mt + 128);
    mA3 = *(const float4*)(mt + 132);

#define CDOT(dd, M0, M1) { \
    float4 xa_ = *(const float4*)&xs[(dd) * 132 + ty * 8]; \
    float4 xb_ = *(const float4*)&xs[(dd) * 132 + ty * 8 + 4]; \
    float xv_[8] = {xa_.x, xa_.y, xa_.z, xa_.w, xb_.x, xb_.y, xb_.z, xb_.w}; \
    float mv_[8] = {M0.x, M0.y, M0.z, M0.w, M1.x, M1.y, M1.z, M1.w}; \
    _Pragma("unroll") \
    for (int i_ = 0; i_ < 8; ++i_) \
        _Pragma("unroll") \
        for (int j_ = 0; j_ < 8; ++j_) \
            acc[i_][j_] = fmaf(xv_[i_], mv_[j_], acc[i_][j_]); }

    for (int g = 0; g < 32; g += 2) {
        {
            int gn = (g + 1 < 32) ? g + 1 : 31;
            const float* p = mt + gn * 256;
            mB0 = *(const float4*)(p + 0);
            mB1 = *(const float4*)(p + 4);
            mB2 = *(const float4*)(p + 128);
            mB3 = *(const float4*)(p + 132);
        }
        CDOT(2 * g,     mA0, mA1);
        CDOT(2 * g + 1, mA2, mA3);
        {
            int gn = (g + 2 < 32) ? g + 2 : 31;
            const float* p = mt + gn * 256;
            mA0 = *(const float4*)(p + 0);
            mA1 = *(const float4*)(p + 4);
            mA2 = *(const float4*)(p + 128);
            mA3 = *(const float4*)(p + 132);
        }
        CDOT(2 * g + 2, mB0, mB1);
        CDOT(2 * g + 3, mB2, mB3);
    }
#undef CDOT

    #pragma unroll
    for (int j = 0; j < 8; ++j) {
        const int c = tx * 8 + j;
        float* gp = dists + ((size_t)(bhl * NC_ + c)) * T2_ + t0 + ty * 8;
        *(float4*)gp       = make_float4(acc[0][j], acc[1][j], acc[2][j], acc[3][j]);
        *(float4*)(gp + 4) = make_float4(acc[4][j], acc[5][j], acc[6][j], acc[7][j]);
    }

    #pragma unroll
    for (int i = 0; i < 8; ++i) {
        float bv = -1e30f; int bcid = 0;
        #pragma unroll
        for (int j = 0; j < 8; ++j) {
            float vv = acc[i][j];
            if (vv > bv) { bv = vv; bcid = tx * 8 + j; }
        }
        #pragma unroll
        for (int off = 1; off < 16; off <<= 1) {
            float ov = __shfl_xor(bv, off);
            int   oc = __shfl_xor(bcid, off);
            if (ov > bv || (ov == bv && oc < bcid)) { bv = ov; bcid = oc; }
        }
        if (tx == 0) bcs[ty * 8 + i] = bcid;
    }
    __syncthreads();

    float part = 0.f;
    for (int it = 0; it < 32; ++it) {
        int tl = it * 4 + w;
        int cb = bcs[tl];
        const float* mr = means + ((size_t)(h * NC_ + cb)) * 64;
        float df = xs[lane * 132 + tl] - mr[lane];
        part = fmaf(df, df, part);
    }
    #pragma unroll
    for (int off = 32; off > 0; off >>= 1) part += __shfl_xor(part, off);
    if (lane == 0) ar[w] = part;
    __syncthreads();
    if (tid == 0) atomicAdd(aux, ar[0] + ar[1] + ar[2] + ar[3]);
}

// ---------------------------------------------------------------------------
// K2: top-64 of 8192 — register-resident, 12-bit histogram, parallel
// suffix-scan threshold, exact candidate rank.  (unchanged, passing)
// ---------------------------------------------------------------------------
__device__ __forceinline__ unsigned flip_f32(float f) {
    unsigned bits = __float_as_uint(f);
    return (bits & 0x80000000u) ? ~bits : (bits | 0x80000000u);
}

__global__ __launch_bounds__(256)
void k_topk(const float* __restrict__ dists, int* __restrict__ qidx,
            int* __restrict__ kidx, int bh_base)
{
    __shared__ unsigned hist[4096];
    __shared__ unsigned sfx[256];
    __shared__ unsigned wtot[4];
    __shared__ unsigned cand_u[768];
    __shared__ int      cand_i[768];
    __shared__ int sh[6];

    const int tid   = threadIdx.x;
    const int c     = blockIdx.x;
    const int bhl   = blockIdx.y;
    const int which = blockIdx.z;
    const float* row = dists + ((size_t)(bhl * NC_ + c)) * T2_ + (size_t)which * T_;
    int* outp = (which ? kidx : qidx) + ((size_t)((bh_base + bhl) * NC_ + c)) * WSZ_;

    unsigned u[32];
    {
        const float4* r4 = (const float4*)row;
        #pragma unroll
        for (int it = 0; it < 8; ++it) {
            float4 f = r4[it * 256 + tid];
            u[it * 4 + 0] = flip_f32(f.x);
            u[it * 4 + 1] = flip_f32(f.y);
            u[it * 4 + 2] = flip_f32(f.z);
            u[it * 4 + 3] = flip_f32(f.w);
        }
    }
    for (int i = tid; i < 4096; i += 256) hist[i] = 0;
    if (tid < 6) sh[tid] = (tid < 2) ? -1 : 0;
    __syncthreads();

    #pragma unroll
    for (int j = 0; j < 32; ++j) atomicAdd(&hist[u[j] >> 20], 1u);
    __syncthreads();

    unsigned gs = 0;
    #pragma unroll
    for (int j = 0; j < 16; ++j) gs += hist[tid * 16 + j];

    const int l = tid & 63, w = tid >> 6;
    unsigned sv = gs;
    #pragma unroll
    for (int off = 1; off < 64; off <<= 1) {
        unsigned up = __shfl_down(sv, off);
        if (l + off < 64) sv += up;
    }
    if (l == 0) wtot[w] = sv;
    __syncthreads();
    unsigned hi = 0;
    for (int ww = w + 1; ww < 4; ++ww) hi += wtot[ww];
    unsigned suffix = sv + hi;
    sfx[tid] = suffix;
    if (suffix >= WSZ_) atomicMax(&sh[0], tid);
    __syncthreads();
    const int g1 = sh[0];
    const unsigned above_groups = (g1 < 255) ? sfx[g1 + 1] : 0u;

    if (tid < 16) {
        unsigned bs = above_groups;
        for (int j = 15; j >= tid; --j) bs += hist[g1 * 16 + j];
        if (bs >= WSZ_) atomicMax(&sh[1], g1 * 16 + tid);
    }
    __syncthreads();
    const int b1 = sh[1];
    if (tid == 0) {
        unsigned gt = above_groups;
        for (int j = b1 + 1; j <= g1 * 16 + 15; ++j) gt += hist[j];
        sh[4] = WSZ_ - (int)gt;
    }
    __syncthreads();
    const int kk = sh[4];

    #pragma unroll
    for (int j = 0; j < 32; ++j) {
        int bin = (int)(u[j] >> 20);
        int idx = (j >> 2) * 1024 + tid * 4 + (j & 3);
        if (bin > b1) {
            int p = atomicAdd(&sh[2], 1);
            outp[p] = idx;
        } else if (bin == b1) {
            int p = atomicAdd(&sh[3], 1);
            if (p < 768) { cand_u[p] = u[j]; cand_i[p] = idx; }
        }
    }
    __syncthreads();
    const int G = sh[2];
    const int C = sh[3];

    if (C <= 768) {
        for (int j = tid; j < C; j += 256) {
            unsigned uj = cand_u[j]; int ij = cand_i[j];
            int rank = 0;
            for (int ll = 0; ll < C; ++ll) {
                unsigned ul = cand_u[ll];
                rank += (int)((ul > uj) || (ul == uj && cand_i[ll] < ij));
            }
            if (rank < kk) outp[G + rank] = ij;
        }
        return;
    }

    // fallback: full 4-level radix re-reading global
    unsigned prefix = 0, mask = 0;
    int need = WSZ_;
    for (int shift = 24; shift >= 0; shift -= 8) {
        if (tid < 256) hist[tid] = 0;
        __syncthreads();
        for (int it = 0; it < 32; ++it) {
            unsigned uu = flip_f32(row[it * 256 + tid]);
            if ((uu & mask) == prefix) atomicAdd(&hist[(uu >> shift) & 255u], 1u);
        }
        __syncthreads();
        if (tid == 0) {
            int b = 255;
            int k2 = need;
            while (b > 0) {
                int cnt = (int)hist[b];
                if (k2 - cnt <= 0) break;
                k2 -= cnt; --b;
            }
            sh[0] = k2; sh[1] = b;
        }
        __syncthreads();
        need = sh[0];
        prefix |= ((unsigned)sh[1]) << shift;
        mask   |= 0xFFu << shift;
        __syncthreads();
    }
    if (tid == 0) { sh[2] = 0; sh[3] = 0; }
    __syncthreads();
    const unsigned thr = prefix;
    for (int it = 0; it < 32; ++it) {
        int i = it * 256 + tid;
        unsigned uu = flip_f32(row[i]);
        if (uu > thr) {
            int p = atomicAdd(&sh[2], 1);
            outp[p] = i;
        } else if (uu == thr) {
            int p = atomicAdd(&sh[3], 1);
            if (p < 768) cand_i[p] = i;
        }
    }
    __syncthreads();
    if (tid == 0) {
        int base = sh[2];
        int E = sh[3] < 768 ? sh[3] : 768;
        for (int n = 0; n < need; ++n) {
            int mi = 0x7fffffff, mj = 0;
            for (int j = 0; j < E; ++j) {
                int vv = cand_i[j];
                if (vv < mi) { mi = vv; mj = j; }
            }
            cand_i[mj] = 0x7fffffff;
            outp[base + n] = mi;
        }
    }
}

// ---------------------------------------------------------------------------
// K3-so v3: r4-proven attention body (padded-68 LDS, NO min-waves bound —
// r6's __launch_bounds__(256,4) forced VGPR spills: 20x scratch traffic).
// so/entries gather epilogue, integer packing (no unions).
// grid: (NC, BH)  block: 256
// ---------------------------------------------------------------------------
__global__ __launch_bounds__(256)
void k_attn_w(const float* __restrict__ q, const float* __restrict__ k,
              const float* __restrict__ v, const int* __restrict__ qidx,
              const int* __restrict__ kidx, unsigned short* __restrict__ so,
              int* __restrict__ cnt, int* __restrict__ entries,
              float* __restrict__ out)
{
    __shared__ float As[64 * 68];   // Q, then P
    __shared__ float Bs[64 * 68];   // K, then V
    __shared__ int qi[64], ki[64], lp[64];

    const int tid = threadIdx.x;
    const int c  = blockIdx.x;
    const int bh = blockIdx.y;
    const int* qp = qidx + ((size_t)(bh * NC_ + c)) * WSZ_;
    const int* kp = kidx + ((size_t)(bh * NC_ + c)) * WSZ_;
    if (tid < 64) { qi[tid] = qp[tid]; ki[tid] = kp[tid]; }
    __syncthreads();

    const int grow = tid >> 2, gseg = (tid & 3) * 16;
    {
        const float* qsrc = q + ((size_t)bh * T_ + qi[grow]) * D_ + gseg;
        const float* ksrc = k + ((size_t)bh * T_ + ki[grow]) * D_ + gseg;
        #pragma unroll
        for (int j4 = 0; j4 < 4; ++j4) {
            *(float4*)&As[grow * 68 + gseg + j4 * 4] = ((const float4*)qsrc)[j4];
            *(float4*)&Bs[grow * 68 + gseg + j4 * 4] = ((const float4*)ksrc)[j4];
        }
    }
    __syncthreads();

    const int tx = tid & 15;
    const int ty = tid >> 4;

    float sacc[4][4];
    #pragma unroll
    for (int i = 0; i < 4; ++i)
        #pragma unroll
        for (int j = 0; j < 4; ++j) sacc[i][j] = 0.f;

    for (int kk4 = 0; kk4 < 16; ++kk4) {
        float4 qv[4], kv[4];
        #pragma unroll
        for (int i = 0; i < 4; ++i) qv[i] = *(const float4*)&As[(ty * 4 + i) * 68 + kk4 * 4];
        #pragma unroll
        for (int j = 0; j < 4; ++j) kv[j] = *(const float4*)&Bs[(tx * 4 + j) * 68 + kk4 * 4];
        #pragma unroll
        for (int i = 0; i < 4; ++i)
            #pragma unroll
            for (int j = 0; j < 4; ++j)
                sacc[i][j] = fmaf(qv[i].w, kv[j].w, fmaf(qv[i].z, kv[j].z,
                              fmaf(qv[i].y, kv[j].y, fmaf(qv[i].x, kv[j].x, sacc[i][j]))));
    }
    __syncthreads();

    {
        const float* vsrc = v + ((size_t)bh * T_ + ki[grow]) * D_ + gseg;
        #pragma unroll
        for (int j4 = 0; j4 < 4; ++j4)
            *(float4*)&Bs[grow * 68 + gseg + j4 * 4] = ((const float4*)vsrc)[j4];
    }

    float rinv[4];
    #pragma unroll
    for (int i = 0; i < 4; ++i) {
        float m = fmaxf(fmaxf(sacc[i][0], sacc[i][1]), fmaxf(sacc[i][2], sacc[i][3]));
        m = fmaxf(m, __shfl_xor(m, 1));
        m = fmaxf(m, __shfl_xor(m, 2));
        m = fmaxf(m, __shfl_xor(m, 4));
        m = fmaxf(m, __shfl_xor(m, 8));
        float4 ev;
        ev.x = expf((sacc[i][0] - m) * 0.125f);
        ev.y = expf((sacc[i][1] - m) * 0.125f);
        ev.z = expf((sacc[i][2] - m) * 0.125f);
        ev.w = expf((sacc[i][3] - m) * 0.125f);
        float s = ev.x + ev.y + ev.z + ev.w;
        s += __shfl_xor(s, 1);
        s += __shfl_xor(s, 2);
        s += __shfl_xor(s, 4);
        s += __shfl_xor(s, 8);
        rinv[i] = 1.0f / s;
        *(float4*)&As[(ty * 4 + i) * 68 + tx * 4] = ev;
    }
    __syncthreads();

    float oacc[4][4];
    #pragma unroll
    for (int i = 0; i < 4; ++i)
        #pragma unroll
        for (int j = 0; j < 4; ++j) oacc[i][j] = 0.f;

    for (int jj4 = 0; jj4 < 16; ++jj4) {
        float4 vv[4];
        #pragma unroll
        for (int ll = 0; ll < 4; ++ll) vv[ll] = *(const float4*)&Bs[(jj4 * 4 + ll) * 68 + tx * 4];
        #pragma unroll
        for (int i = 0; i < 4; ++i) {
            float4 pv = *(const float4*)&As[(ty * 4 + i) * 68 + jj4 * 4];
            oacc[i][0] = fmaf(pv.w, vv[3].x, fmaf(pv.z, vv[2].x, fmaf(pv.y, vv[1].x, fmaf(pv.x, vv[0].x, oacc[i][0]))));
            oacc[i][1] = fmaf(pv.w, vv[3].y, fmaf(pv.z, vv[2].y, fmaf(pv.y, vv[1].y, fmaf(pv.x, vv[0].y, oacc[i][1]))));
            oacc[i][2] = fmaf(pv.w, vv[3].z, fmaf(pv.z, vv[2].z, fmaf(pv.y, vv[1].z, fmaf(pv.x, vv[0].z, oacc[i][2]))));
            oacc[i][3] = fmaf(pv.w, vv[3].w, fmaf(pv.z, vv[2].w, fmaf(pv.y, vv[1].w, fmaf(pv.x, vv[0].w, oacc[i][3]))));
        }
    }

    // ---- registration: one thread per row claims an inverse-list slot
    if (tx == 0) {
        #pragma unroll
        for (int i = 0; i < 4; ++i) {
            int r = ty * 4 + i;
            int t = qi[r];
            int p = atomicAdd(&cnt[(size_t)bh * T_ + t], 1);
            if (p < CAP_) entries[((size_t)bh * T_ + t) * CAP_ + p] = c * WSZ_ + r;
            lp[r] = p;
        }
    }
    __syncthreads();

    // ---- emit so rows (always); overflow rows also atomic into out (rare)
    #pragma unroll
    for (int i = 0; i < 4; ++i) {
        const int r = ty * 4 + i;
        float o0 = oacc[i][0] * rinv[i];
        float o1 = oacc[i][1] * rinv[i];
        float o2 = oacc[i][2] * rinv[i];
        float o3 = oacc[i][3] * rinv[i];
        unsigned short* dst = so + (((size_t)(bh * NC_ + c)) * WSZ_ + r) * D_ + tx * 4;
        uint2 pk;
        pk.x = f2bf_u(o0) | (f2bf_u(o1) << 16);
        pk.y = f2bf_u(o2) | (f2bf_u(o3) << 16);
        *(uint2*)dst = pk;
        if (lp[r] >= CAP_) {
            float* ob = out + ((size_t)bh * T_ + qi[r]) * D_ + tx * 4;
            atomicAdd(ob + 0, o0); atomicAdd(ob + 1, o1);
            atomicAdd(ob + 2, o2); atomicAdd(ob + 3, o3);
        }
    }
}

// ---------------------------------------------------------------------------
// K4-so: gather finalize: out[t] = (sum of registered so rows + overflow)/(n+eps)
// grid: (T/16, BH)  block: 256
// ---------------------------------------------------------------------------
__global__ __launch_bounds__(256)
void k_gather(const unsigned short* __restrict__ so, const int* __restrict__ cnt,
              const int* __restrict__ entries, float* __restrict__ out,
              const float* __restrict__ aux)
{
    const int tid = threadIdx.x;
    const int tk  = blockIdx.x * 16 + (tid >> 4);
    const int bh  = blockIdx.y;
    const int d4  = (tid & 15) * 4;
    const size_t tix = (size_t)bh * T_ + tk;

    const int n = cnt[tix];
    const int m = n < CAP_ ? n : CAP_;
    const int* ep = entries + tix * CAP_;

    float a0 = 0.f, a1 = 0.f, a2 = 0.f, a3 = 0.f;
    for (int j = 0; j < m; ++j) {
        int e = ep[j];
        const unsigned short* sp = so + ((size_t)bh * (NC_ * WSZ_) + e) * D_ + d4;
        uint2 raw = *(const uint2*)sp;
        a0 += bf2f((unsigned short)(raw.x & 0xffffu));
        a1 += bf2f((unsigned short)(raw.x >> 16));
        a2 += bf2f((unsigned short)(raw.y & 0xffffu));
        a3 += bf2f((unsigned short)(raw.y >> 16));
    }
    float* op = out + tix * D_ + d4;
    float4 pr = *(float4*)op;                 // overflow base (normally 0)
    float inv = 1.0f / ((float)n + 1e-5f);
    float4 r;
    r.x = (a0 + pr.x) * inv;
    r.y = (a1 + pr.y) * inv;
    r.z = (a2 + pr.z) * inv;
    r.w = (a3 + pr.w) * inv;
    *(float4*)op = r;

    if (blockIdx.x == 0 && bh == 0 && tid == 0)
        out[(size_t)BH_ * T_ * D_] = aux[0] * 1.4901161193847656e-12f;
}

// ---------------------------------------------------------------------------
// K3/K4 fallback (small-ws): exact atomic-scatter path
// ---------------------------------------------------------------------------
__global__ __launch_bounds__(256)
void k_attn(const float* __restrict__ q, const float* __restrict__ k,
            const float* __restrict__ v, const int* __restrict__ qidx,
            const int* __restrict__ kidx, float* __restrict__ out,
            float* __restrict__ den)
{
    __shared__ float As[64 * 68];
    __shared__ float Bs[64 * 68];
    __shared__ int qi[64], ki[64];

    const int tid = threadIdx.x;
    const int c  = blockIdx.x;
    const int bh = blockIdx.y;
    const int* qp = qidx + ((size_t)(bh * NC_ + c)) * WSZ_;
    const int* kp = kidx + ((size_t)(bh * NC_ + c)) * WSZ_;
    if (tid < 64) { qi[tid] = qp[tid]; ki[tid] = kp[tid]; }
    __syncthreads();

    const int grow = tid >> 2, gseg = (tid & 3) * 16;
    {
        const float* qsrc = q + ((size_t)bh * T_ + qi[grow]) * D_ + gseg;
        const float* ksrc = k + ((size_t)bh * T_ + ki[grow]) * D_ + gseg;
        #pragma unroll
        for (int j4 = 0; j4 < 4; ++j4) {
            *(float4*)&As[grow * 68 + gseg + j4 * 4] = ((const float4*)qsrc)[j4];
            *(float4*)&Bs[grow * 68 + gseg + j4 * 4] = ((const float4*)ksrc)[j4];
        }
    }
    __syncthreads();

    const int tx = tid & 15;
    const int ty = tid >> 4;

    float sacc[4][4];
    #pragma unroll
    for (int i = 0; i < 4; ++i)
        #pragma unroll
        for (int j = 0; j < 4; ++j) sacc[i][j] = 0.f;

    for (int kk4 = 0; kk4 < 16; ++kk4) {
        float4 qv[4], kv[4];
        #pragma unroll
        for (int i = 0; i < 4; ++i) qv[i] = *(const float4*)&As[(ty * 4 + i) * 68 + kk4 * 4];
        #pragma unroll
        for (int j = 0; j < 4; ++j) kv[j] = *(const float4*)&Bs[(tx * 4 + j) * 68 + kk4 * 4];
        #pragma unroll
        for (int i = 0; i < 4; ++i)
            #pragma unroll
            for (int j = 0; j < 4; ++j)
                sacc[i][j] = fmaf(qv[i].w, kv[j].w, fmaf(qv[i].z, kv[j].z,
                              fmaf(qv[i].y, kv[j].y, fmaf(qv[i].x, kv[j].x, sacc[i][j]))));
    }
    __syncthreads();

    {
        const float* vsrc = v + ((size_t)bh * T_ + ki[grow]) * D_ + gseg;
        #pragma unroll
        for (int j4 = 0; j4 < 4; ++j4)
            *(float4*)&Bs[grow * 68 + gseg + j4 * 4] = ((const float4*)vsrc)[j4];
    }

    float rinv[4];
    #pragma unroll
    for (int i = 0; i < 4; ++i) {
        float m = fmaxf(fmaxf(sacc[i][0], sacc[i][1]), fmaxf(sacc[i][2], sacc[i][3]));
        m = fmaxf(m, __shfl_xor(m, 1));
        m = fmaxf(m, __shfl_xor(m, 2));
        m = fmaxf(m, __shfl_xor(m, 4));
        m = fmaxf(m, __shfl_xor(m, 8));
        float4 ev;
        ev.x = expf((sacc[i][0] - m) * 0.125f);
        ev.y = expf((sacc[i][1] - m) * 0.125f);
        ev.z = expf((sacc[i][2] - m) * 0.125f);
        ev.w = expf((sacc[i][3] - m) * 0.125f);
        float s = ev.x + ev.y + ev.z + ev.w;
        s += __shfl_xor(s, 1);
        s += __shfl_xor(s, 2);
        s += __shfl_xor(s, 4);
        s += __shfl_xor(s, 8);
        rinv[i] = 1.0f / s;
        *(float4*)&As[(ty * 4 + i) * 68 + tx * 4] = ev;
    }
    __syncthreads();

    float oacc[4][4];
    #pragma unroll
    for (int i = 0; i < 4; ++i)
        #pragma unroll
        for (int j = 0; j < 4; ++j) oacc[i][j] = 0.f;

    for (int jj4 = 0; jj4 < 16; ++jj4) {
        float4 vv[4];
        #pragma unroll
        for (int ll = 0; ll < 4; ++ll) vv[ll] = *(const float4*)&Bs[(jj4 * 4 + ll) * 68 + tx * 4];
        #pragma unroll
        for (int i = 0; i < 4; ++i) {
            float4 pv = *(const float4*)&As[(ty * 4 + i) * 68 + jj4 * 4];
            oacc[i][0] = fmaf(pv.w, vv[3].x, fmaf(pv.z, vv[2].x, fmaf(pv.y, vv[1].x, fmaf(pv.x, vv[0].x, oacc[i][0]))));
            oacc[i][1] = fmaf(pv.w, vv[3].y, fmaf(pv.z, vv[2].y, fmaf(pv.y, vv[1].y, fmaf(pv.x, vv[0].y, oacc[i][1]))));
            oacc[i][2] = fmaf(pv.w, vv[3].z, fmaf(pv.z, vv[2].z, fmaf(pv.y, vv[1].z, fmaf(pv.x, vv[0].z, oacc[i][2]))));
            oacc[i][3] = fmaf(pv.w, vv[3].w, fmaf(pv.z, vv[2].w, fmaf(pv.y, vv[1].w, fmaf(pv.x, vv[0].w, oacc[i][3]))));
        }
    }

    #pragma unroll
    for (int i = 0; i < 4; ++i) {
        const int r = ty * 4 + i;
        float* obase = out + ((size_t)bh * T_ + qi[r]) * D_ + tx * 4;
        #pragma unroll
        for (int j = 0; j < 4; ++j) atomicAdd(obase + j, oacc[i][j] * rinv[i]);
    }
    if (tx == 0) {
        #pragma unroll
        for (int i = 0; i < 4; ++i) atomicAdd(den + (size_t)bh * T_ + qi[ty * 4 + i], 1.0f);
    }
}

__global__ __launch_bounds__(256)
void k_final(float* __restrict__ out, const float* __restrict__ den,
             const float* __restrict__ aux)
{
    size_t gid = (size_t)blockIdx.x * 256 + threadIdx.x;
    float4* o4 = (float4*)out;
    float d = den[gid >> 4] + 1e-5f;
    float4 x = o4[gid];
    x.x = x.x / d; x.y = x.y / d; x.z = x.z / d; x.w = x.w / d;
    o4[gid] = x;
    if (gid == 0) out[(size_t)BH_ * T_ * D_] = aux[0] * 1.4901161193847656e-12f;
}

extern "C" void kernel_launch(void* const* d_in, const int* in_sizes, int n_in,
                              void* d_out, int out_size, void* d_ws, size_t ws_size,
                              hipStream_t stream) {
    const float* q     = (const float*)d_in[0];
    const float* k     = (const float*)d_in[1];
    const float* v     = (const float*)d_in[2];
    const float* means = (const float*)d_in[3];
    float* out = (float*)d_out;
    char*  ws  = (char*)d_ws;
    float* aux    = (float*)(ws + OFF_AUX);
    float* den    = (float*)(ws + OFF_DEN);     // cnt (int) in so-path
    int*   qidx   = (int*)(ws + OFF_QIDX);
    int*   kidx   = (int*)(ws + OFF_KIDX);
    float* meanst = (float*)(ws + OFF_MEANST);
    float* dists  = (float*)(ws + OFF_DISTS);

    hipMemsetAsync(out, 0, (size_t)((size_t)BH_ * T_ * D_ + 1) * 4, stream);
    hipMemsetAsync(ws, 0, (size_t)OFF_QIDX, stream);   // aux + den/cnt

    k_meanst<<<256, 256, 0, stream>>>(means, meanst);

    size_t region = (ws_size > OFF_DISTS) ? ws_size - (size_t)OFF_DISTS : 0;
    size_t per_bh = (size_t)NC_ * T2_ * 4;   // 8 MB
    int nbh = (int)(region / per_bh);
    nbh = nbh < 1 ? 1 : (nbh > BH_ ? BH_ : nbh);
    const bool sopath = region >= (SO_BYTES + ENTRIES_BYTES);

    for (int bh_base = 0; bh_base < BH_; bh_base += nbh) {
        int cur = BH_ - bh_base < nbh ? BH_ - bh_base : nbh;
        k_dists<<<dim3(T2_ / 128, cur), 256, 0, stream>>>(q, k, means, meanst, dists, aux, bh_base);
        k_topk <<<dim3(NC_, cur, 2),    256, 0, stream>>>(dists, qidx, kidx, bh_base);
    }

    if (sopath) {
        unsigned short* so = (unsigned short*)(ws + OFF_DISTS);
        int* entries = (int*)(ws + OFF_DISTS + SO_BYTES);
        k_attn_w<<<dim3(NC_, BH_), 256, 0, stream>>>(q, k, v, qidx, kidx,
                                                     so, (int*)den, entries, out);
        k_gather<<<dim3(T_ / 16, BH_), 256, 0, stream>>>(so, (int*)den, entries, out, aux);
    } else {
        k_attn<<<dim3(NC_, BH_), 256, 0, stream>>>(q, k, v, qidx, kidx, out, den);
        k_final<<<(BH_ * T_ * D_ / 4 + 255) / 256, 256, 0, stream>>>(out, den, aux);
    }
}

// Round 8
// 1492.607 us; speedup vs baseline: 2.3059x; 1.2029x over previous
//
#include <hip/hip_runtime.h>
#include <hip/hip_bf16.h>
#include <math.h>

#define B_ 8
#define H_ 8
#define T_ 8192
#define D_ 64
#define NC_ 128
#define WSZ_ 64
#define T2_ (2*T_)
#define BH_ (B_*H_)
#define CAP_ 16

// workspace layout (bytes)
#define OFF_AUX    0
#define OFF_DEN    4096                              // den (fallback) / cnt (so-path), BH*T*4
#define OFF_QIDX   (OFF_DEN  + BH_*T_*4)
#define OFF_KIDX   (OFF_QIDX + BH_*NC_*WSZ_*4)
#define OFF_MEANST (OFF_KIDX + BH_*NC_*WSZ_*4)
#define OFF_DISTS  (OFF_MEANST + H_*NC_*D_*4)
// dists region: nbh*NC_*T2_*4 bytes; reused after topk as:
//   so      (bf16): BH*NC*WSZ*D*2 = 67.1 MB
//   entries (int) : BH*T*CAP*4    = 32   MB
#define SO_BYTES      ((size_t)BH_*NC_*WSZ_*D_*2)
#define ENTRIES_BYTES ((size_t)BH_*T_*CAP_*4)

__device__ __forceinline__ unsigned f2bf_u(float f) {
    union { __hip_bfloat16 b; unsigned short s; } cv;
    cv.b = __float2bfloat16(f);
    return (unsigned)cv.s;
}
__device__ __forceinline__ float bf2f(unsigned short s) {
    return __uint_as_float(((unsigned)s) << 16);
}

// ---------------------------------------------------------------------------
// K0: transpose means [h][c][d] -> meanst [h][d][c]
// ---------------------------------------------------------------------------
__global__ __launch_bounds__(256)
void k_meanst(const float* __restrict__ means, float* __restrict__ meanst)
{
    int gid = blockIdx.x * 256 + threadIdx.x;
    int h = gid >> 13;
    int rem = gid & 8191;
    int d = rem >> 7;
    int c = rem & 127;
    meanst[gid] = means[((h << 7) | c) * 64 + d];
}

// ---------------------------------------------------------------------------
// K1 (r5-exact, proven 510us / VGPR 56 / no spill): dists + argmax + aux.
// 8tok x 8clu register tile; NO register prefetch (r7 lesson: prefetch
// buffers under the (256,4) bound spilled the AGPR-resident accumulator
// -> 2x write traffic). FMA order ascending-d -> bitwise-identical dists.
// grid: (T2/128, nbh)  block: 256
// ---------------------------------------------------------------------------
__global__ __launch_bounds__(256, 4)
void k_dists(const float* __restrict__ q, const float* __restrict__ k,
             const float* __restrict__ means, const float* __restrict__ meanst,
             float* __restrict__ dists, float* __restrict__ aux, int bh_base)
{
    __shared__ float xs[64 * 132];   // [d][token], stride 132
    __shared__ int   bcs[128];
    __shared__ float ar[4];

    const int tid = threadIdx.x;
    const int bhl = blockIdx.y;
    const int bh  = bh_base + bhl;
    const int h   = bh % H_;
    const int t0  = blockIdx.x * 128;

    // ---- phase 1: load 128 token rows, normalize, store transposed
    const int lane = tid & 63;
    const int w    = tid >> 6;
    for (int it = 0; it < 32; ++it) {
        int tl = it * 4 + w;
        int gt = t0 + tl;
        const float* src = (gt < T_)
            ? (q + ((size_t)bh * T_ + gt) * D_)
            : (k + ((size_t)bh * T_ + (gt - T_)) * D_);
        float vv = src[lane];
        float s = vv * vv;
        #pragma unroll
        for (int off = 32; off > 0; off >>= 1) s += __shfl_xor(s, off);
        float norm = fmaxf(sqrtf(s), 1e-12f);
        xs[lane * 132 + tl] = vv / norm;
    }
    __syncthreads();

    // ---- phase 2: 8x8 tile per thread over d
    const int ty = tid >> 4;     // token group
    const int tx = tid & 15;     // cluster group
    float acc[8][8];
    #pragma unroll
    for (int i = 0; i < 8; ++i)
        #pragma unroll
        for (int j = 0; j < 8; ++j) acc[i][j] = 0.f;

    const float* mt = meanst + (size_t)h * (64 * 128) + tx * 8;
    #pragma unroll 4
    for (int d = 0; d < 64; ++d) {
        float4 ma = *(const float4*)(mt + d * 128);
        float4 mb = *(const float4*)(mt + d * 128 + 4);
        float4 xa = *(const float4*)&xs[d * 132 + ty * 8];
        float4 xb = *(const float4*)&xs[d * 132 + ty * 8 + 4];
        float xv[8] = {xa.x, xa.y, xa.z, xa.w, xb.x, xb.y, xb.z, xb.w};
        float mv[8] = {ma.x, ma.y, ma.z, ma.w, mb.x, mb.y, mb.z, mb.w};
        #pragma unroll
        for (int i = 0; i < 8; ++i)
            #pragma unroll
            for (int j = 0; j < 8; ++j)
                acc[i][j] = fmaf(xv[i], mv[j], acc[i][j]);
    }

    // ---- phase 3: direct transposed global store
    #pragma unroll
    for (int j = 0; j < 8; ++j) {
        const int c = tx * 8 + j;
        float* gp = dists + ((size_t)(bhl * NC_ + c)) * T2_ + t0 + ty * 8;
        *(float4*)gp       = make_float4(acc[0][j], acc[1][j], acc[2][j], acc[3][j]);
        *(float4*)(gp + 4) = make_float4(acc[4][j], acc[5][j], acc[6][j], acc[7][j]);
    }

    // ---- phase 4: argmax across clusters (16-lane groups share tokens)
    #pragma unroll
    for (int i = 0; i < 8; ++i) {
        float bv = -1e30f; int bcid = 0;
        #pragma unroll
        for (int j = 0; j < 8; ++j) {
            float vv = acc[i][j];
            if (vv > bv) { bv = vv; bcid = tx * 8 + j; }
        }
        #pragma unroll
        for (int off = 1; off < 16; off <<= 1) {
            float ov = __shfl_xor(bv, off);
            int   oc = __shfl_xor(bcid, off);
            if (ov > bv || (ov == bv && oc < bcid)) { bv = ov; bcid = oc; }
        }
        if (tx == 0) bcs[ty * 8 + i] = bcid;
    }
    __syncthreads();

    // ---- phase 5: aux = sum (xn - mean_best)^2
    float part = 0.f;
    for (int it = 0; it < 32; ++it) {
        int tl = it * 4 + w;
        int cb = bcs[tl];
        const float* mr = means + ((size_t)(h * NC_ + cb)) * 64;
        float df = xs[lane * 132 + tl] - mr[lane];
        part = fmaf(df, df, part);
    }
    #pragma unroll
    for (int off = 32; off > 0; off >>= 1) part += __shfl_xor(part, off);
    if (lane == 0) ar[w] = part;
    __syncthreads();
    if (tid == 0) atomicAdd(aux, ar[0] + ar[1] + ar[2] + ar[3]);
}

// ---------------------------------------------------------------------------
// K2: top-64 of 8192 — register-resident, 12-bit histogram, parallel
// suffix-scan threshold, exact candidate rank.  (unchanged, passing)
// ---------------------------------------------------------------------------
__device__ __forceinline__ unsigned flip_f32(float f) {
    unsigned bits = __float_as_uint(f);
    return (bits & 0x80000000u) ? ~bits : (bits | 0x80000000u);
}

__global__ __launch_bounds__(256)
void k_topk(const float* __restrict__ dists, int* __restrict__ qidx,
            int* __restrict__ kidx, int bh_base)
{
    __shared__ unsigned hist[4096];
    __shared__ unsigned sfx[256];
    __shared__ unsigned wtot[4];
    __shared__ unsigned cand_u[768];
    __shared__ int      cand_i[768];
    __shared__ int sh[6];

    const int tid   = threadIdx.x;
    const int c     = blockIdx.x;
    const int bhl   = blockIdx.y;
    const int which = blockIdx.z;
    const float* row = dists + ((size_t)(bhl * NC_ + c)) * T2_ + (size_t)which * T_;
    int* outp = (which ? kidx : qidx) + ((size_t)((bh_base + bhl) * NC_ + c)) * WSZ_;

    unsigned u[32];
    {
        const float4* r4 = (const float4*)row;
        #pragma unroll
        for (int it = 0; it < 8; ++it) {
            float4 f = r4[it * 256 + tid];
            u[it * 4 + 0] = flip_f32(f.x);
            u[it * 4 + 1] = flip_f32(f.y);
            u[it * 4 + 2] = flip_f32(f.z);
            u[it * 4 + 3] = flip_f32(f.w);
        }
    }
    for (int i = tid; i < 4096; i += 256) hist[i] = 0;
    if (tid < 6) sh[tid] = (tid < 2) ? -1 : 0;
    __syncthreads();

    #pragma unroll
    for (int j = 0; j < 32; ++j) atomicAdd(&hist[u[j] >> 20], 1u);
    __syncthreads();

    unsigned gs = 0;
    #pragma unroll
    for (int j = 0; j < 16; ++j) gs += hist[tid * 16 + j];

    const int l = tid & 63, w = tid >> 6;
    unsigned sv = gs;
    #pragma unroll
    for (int off = 1; off < 64; off <<= 1) {
        unsigned up = __shfl_down(sv, off);
        if (l + off < 64) sv += up;
    }
    if (l == 0) wtot[w] = sv;
    __syncthreads();
    unsigned hi = 0;
    for (int ww = w + 1; ww < 4; ++ww) hi += wtot[ww];
    unsigned suffix = sv + hi;
    sfx[tid] = suffix;
    if (suffix >= WSZ_) atomicMax(&sh[0], tid);
    __syncthreads();
    const int g1 = sh[0];
    const unsigned above_groups = (g1 < 255) ? sfx[g1 + 1] : 0u;

    if (tid < 16) {
        unsigned bs = above_groups;
        for (int j = 15; j >= tid; --j) bs += hist[g1 * 16 + j];
        if (bs >= WSZ_) atomicMax(&sh[1], g1 * 16 + tid);
    }
    __syncthreads();
    const int b1 = sh[1];
    if (tid == 0) {
        unsigned gt = above_groups;
        for (int j = b1 + 1; j <= g1 * 16 + 15; ++j) gt += hist[j];
        sh[4] = WSZ_ - (int)gt;
    }
    __syncthreads();
    const int kk = sh[4];

    #pragma unroll
    for (int j = 0; j < 32; ++j) {
        int bin = (int)(u[j] >> 20);
        int idx = (j >> 2) * 1024 + tid * 4 + (j & 3);
        if (bin > b1) {
            int p = atomicAdd(&sh[2], 1);
            outp[p] = idx;
        } else if (bin == b1) {
            int p = atomicAdd(&sh[3], 1);
            if (p < 768) { cand_u[p] = u[j]; cand_i[p] = idx; }
        }
    }
    __syncthreads();
    const int G = sh[2];
    const int C = sh[3];

    if (C <= 768) {
        for (int j = tid; j < C; j += 256) {
            unsigned uj = cand_u[j]; int ij = cand_i[j];
            int rank = 0;
            for (int ll = 0; ll < C; ++ll) {
                unsigned ul = cand_u[ll];
                rank += (int)((ul > uj) || (ul == uj && cand_i[ll] < ij));
            }
            if (rank < kk) outp[G + rank] = ij;
        }
        return;
    }

    // fallback: full 4-level radix re-reading global
    unsigned prefix = 0, mask = 0;
    int need = WSZ_;
    for (int shift = 24; shift >= 0; shift -= 8) {
        if (tid < 256) hist[tid] = 0;
        __syncthreads();
        for (int it = 0; it < 32; ++it) {
            unsigned uu = flip_f32(row[it * 256 + tid]);
            if ((uu & mask) == prefix) atomicAdd(&hist[(uu >> shift) & 255u], 1u);
        }
        __syncthreads();
        if (tid == 0) {
            int b = 255;
            int k2 = need;
            while (b > 0) {
                int cnt = (int)hist[b];
                if (k2 - cnt <= 0) break;
                k2 -= cnt; --b;
            }
            sh[0] = k2; sh[1] = b;
        }
        __syncthreads();
        need = sh[0];
        prefix |= ((unsigned)sh[1]) << shift;
        mask   |= 0xFFu << shift;
        __syncthreads();
    }
    if (tid == 0) { sh[2] = 0; sh[3] = 0; }
    __syncthreads();
    const unsigned thr = prefix;
    for (int it = 0; it < 32; ++it) {
        int i = it * 256 + tid;
        unsigned uu = flip_f32(row[i]);
        if (uu > thr) {
            int p = atomicAdd(&sh[2], 1);
            outp[p] = i;
        } else if (uu == thr) {
            int p = atomicAdd(&sh[3], 1);
            if (p < 768) cand_i[p] = i;
        }
    }
    __syncthreads();
    if (tid == 0) {
        int base = sh[2];
        int E = sh[3] < 768 ? sh[3] : 768;
        for (int n = 0; n < need; ++n) {
            int mi = 0x7fffffff, mj = 0;
            for (int j = 0; j < E; ++j) {
                int vv = cand_i[j];
                if (vv < mi) { mi = vv; mj = j; }
            }
            cand_i[mj] = 0x7fffffff;
            outp[base + n] = mi;
        }
    }
}

// ---------------------------------------------------------------------------
// K3-so: r4-proven attention body (padded-68 LDS, no min-waves bound) +
// so/entries gather epilogue, integer packing.  (unchanged from r7)
// grid: (NC, BH)  block: 256
// ---------------------------------------------------------------------------
__global__ __launch_bounds__(256)
void k_attn_w(const float* __restrict__ q, const float* __restrict__ k,
              const float* __restrict__ v, const int* __restrict__ qidx,
              const int* __restrict__ kidx, unsigned short* __restrict__ so,
              int* __restrict__ cnt, int* __restrict__ entries,
              float* __restrict__ out)
{
    __shared__ float As[64 * 68];   // Q, then P
    __shared__ float Bs[64 * 68];   // K, then V
    __shared__ int qi[64], ki[64], lp[64];

    const int tid = threadIdx.x;
    const int c  = blockIdx.x;
    const int bh = blockIdx.y;
    const int* qp = qidx + ((size_t)(bh * NC_ + c)) * WSZ_;
    const int* kp = kidx + ((size_t)(bh * NC_ + c)) * WSZ_;
    if (tid < 64) { qi[tid] = qp[tid]; ki[tid] = kp[tid]; }
    __syncthreads();

    const int grow = tid >> 2, gseg = (tid & 3) * 16;
    {
        const float* qsrc = q + ((size_t)bh * T_ + qi[grow]) * D_ + gseg;
        const float* ksrc = k + ((size_t)bh * T_ + ki[grow]) * D_ + gseg;
        #pragma unroll
        for (int j4 = 0; j4 < 4; ++j4) {
            *(float4*)&As[grow * 68 + gseg + j4 * 4] = ((const float4*)qsrc)[j4];
            *(float4*)&Bs[grow * 68 + gseg + j4 * 4] = ((const float4*)ksrc)[j4];
        }
    }
    __syncthreads();

    const int tx = tid & 15;
    const int ty = tid >> 4;

    float sacc[4][4];
    #pragma unroll
    for (int i = 0; i < 4; ++i)
        #pragma unroll
        for (int j = 0; j < 4; ++j) sacc[i][j] = 0.f;

    for (int kk4 = 0; kk4 < 16; ++kk4) {
        float4 qv[4], kv[4];
        #pragma unroll
        for (int i = 0; i < 4; ++i) qv[i] = *(const float4*)&As[(ty * 4 + i) * 68 + kk4 * 4];
        #pragma unroll
        for (int j = 0; j < 4; ++j) kv[j] = *(const float4*)&Bs[(tx * 4 + j) * 68 + kk4 * 4];
        #pragma unroll
        for (int i = 0; i < 4; ++i)
            #pragma unroll
            for (int j = 0; j < 4; ++j)
                sacc[i][j] = fmaf(qv[i].w, kv[j].w, fmaf(qv[i].z, kv[j].z,
                              fmaf(qv[i].y, kv[j].y, fmaf(qv[i].x, kv[j].x, sacc[i][j]))));
    }
    __syncthreads();

    {
        const float* vsrc = v + ((size_t)bh * T_ + ki[grow]) * D_ + gseg;
        #pragma unroll
        for (int j4 = 0; j4 < 4; ++j4)
            *(float4*)&Bs[grow * 68 + gseg + j4 * 4] = ((const float4*)vsrc)[j4];
    }

    float rinv[4];
    #pragma unroll
    for (int i = 0; i < 4; ++i) {
        float m = fmaxf(fmaxf(sacc[i][0], sacc[i][1]), fmaxf(sacc[i][2], sacc[i][3]));
        m = fmaxf(m, __shfl_xor(m, 1));
        m = fmaxf(m, __shfl_xor(m, 2));
        m = fmaxf(m, __shfl_xor(m, 4));
        m = fmaxf(m, __shfl_xor(m, 8));
        float4 ev;
        ev.x = expf((sacc[i][0] - m) * 0.125f);
        ev.y = expf((sacc[i][1] - m) * 0.125f);
        ev.z = expf((sacc[i][2] - m) * 0.125f);
        ev.w = expf((sacc[i][3] - m) * 0.125f);
        float s = ev.x + ev.y + ev.z + ev.w;
        s += __shfl_xor(s, 1);
        s += __shfl_xor(s, 2);
        s += __shfl_xor(s, 4);
        s += __shfl_xor(s, 8);
        rinv[i] = 1.0f / s;
        *(float4*)&As[(ty * 4 + i) * 68 + tx * 4] = ev;
    }
    __syncthreads();

    float oacc[4][4];
    #pragma unroll
    for (int i = 0; i < 4; ++i)
        #pragma unroll
        for (int j = 0; j < 4; ++j) oacc[i][j] = 0.f;

    for (int jj4 = 0; jj4 < 16; ++jj4) {
        float4 vv[4];
        #pragma unroll
        for (int ll = 0; ll < 4; ++ll) vv[ll] = *(const float4*)&Bs[(jj4 * 4 + ll) * 68 + tx * 4];
        #pragma unroll
        for (int i = 0; i < 4; ++i) {
            float4 pv = *(const float4*)&As[(ty * 4 + i) * 68 + jj4 * 4];
            oacc[i][0] = fmaf(pv.w, vv[3].x, fmaf(pv.z, vv[2].x, fmaf(pv.y, vv[1].x, fmaf(pv.x, vv[0].x, oacc[i][0]))));
            oacc[i][1] = fmaf(pv.w, vv[3].y, fmaf(pv.z, vv[2].y, fmaf(pv.y, vv[1].y, fmaf(pv.x, vv[0].y, oacc[i][1]))));
            oacc[i][2] = fmaf(pv.w, vv[3].z, fmaf(pv.z, vv[2].z, fmaf(pv.y, vv[1].z, fmaf(pv.x, vv[0].z, oacc[i][2]))));
            oacc[i][3] = fmaf(pv.w, vv[3].w, fmaf(pv.z, vv[2].w, fmaf(pv.y, vv[1].w, fmaf(pv.x, vv[0].w, oacc[i][3]))));
        }
    }

    // ---- registration: one thread per row claims an inverse-list slot
    if (tx == 0) {
        #pragma unroll
        for (int i = 0; i < 4; ++i) {
            int r = ty * 4 + i;
            int t = qi[r];
            int p = atomicAdd(&cnt[(size_t)bh * T_ + t], 1);
            if (p < CAP_) entries[((size_t)bh * T_ + t) * CAP_ + p] = c * WSZ_ + r;
            lp[r] = p;
        }
    }
    __syncthreads();

    // ---- emit so rows (always); overflow rows also atomic into out (rare)
    #pragma unroll
    for (int i = 0; i < 4; ++i) {
        const int r = ty * 4 + i;
        float o0 = oacc[i][0] * rinv[i];
        float o1 = oacc[i][1] * rinv[i];
        float o2 = oacc[i][2] * rinv[i];
        float o3 = oacc[i][3] * rinv[i];
        unsigned short* dst = so + (((size_t)(bh * NC_ + c)) * WSZ_ + r) * D_ + tx * 4;
        uint2 pk;
        pk.x = f2bf_u(o0) | (f2bf_u(o1) << 16);
        pk.y = f2bf_u(o2) | (f2bf_u(o3) << 16);
        *(uint2*)dst = pk;
        if (lp[r] >= CAP_) {
            float* ob = out + ((size_t)bh * T_ + qi[r]) * D_ + tx * 4;
            atomicAdd(ob + 0, o0); atomicAdd(ob + 1, o1);
            atomicAdd(ob + 2, o2); atomicAdd(ob + 3, o3);
        }
    }
}

// ---------------------------------------------------------------------------
// K4-so: gather finalize: out[t] = (sum of registered so rows + overflow)/(n+eps)
// grid: (T/16, BH)  block: 256
// ---------------------------------------------------------------------------
__global__ __launch_bounds__(256)
void k_gather(const unsigned short* __restrict__ so, const int* __restrict__ cnt,
              const int* __restrict__ entries, float* __restrict__ out,
              const float* __restrict__ aux)
{
    const int tid = threadIdx.x;
    const int tk  = blockIdx.x * 16 + (tid >> 4);
    const int bh  = blockIdx.y;
    const int d4  = (tid & 15) * 4;
    const size_t tix = (size_t)bh * T_ + tk;

    const int n = cnt[tix];
    const int m = n < CAP_ ? n : CAP_;
    const int* ep = entries + tix * CAP_;

    float a0 = 0.f, a1 = 0.f, a2 = 0.f, a3 = 0.f;
    for (int j = 0; j < m; ++j) {
        int e = ep[j];
        const unsigned short* sp = so + ((size_t)bh * (NC_ * WSZ_) + e) * D_ + d4;
        uint2 raw = *(const uint2*)sp;
        a0 += bf2f((unsigned short)(raw.x & 0xffffu));
        a1 += bf2f((unsigned short)(raw.x >> 16));
        a2 += bf2f((unsigned short)(raw.y & 0xffffu));
        a3 += bf2f((unsigned short)(raw.y >> 16));
    }
    float* op = out + tix * D_ + d4;
    float4 pr = *(float4*)op;                 // overflow base (normally 0)
    float inv = 1.0f / ((float)n + 1e-5f);
    float4 r;
    r.x = (a0 + pr.x) * inv;
    r.y = (a1 + pr.y) * inv;
    r.z = (a2 + pr.z) * inv;
    r.w = (a3 + pr.w) * inv;
    *(float4*)op = r;

    if (blockIdx.x == 0 && bh == 0 && tid == 0)
        out[(size_t)BH_ * T_ * D_] = aux[0] * 1.4901161193847656e-12f;
}

// ---------------------------------------------------------------------------
// K3/K4 fallback (small-ws): exact atomic-scatter path
// ---------------------------------------------------------------------------
__global__ __launch_bounds__(256)
void k_attn(const float* __restrict__ q, const float* __restrict__ k,
            const float* __restrict__ v, const int* __restrict__ qidx,
            const int* __restrict__ kidx, float* __restrict__ out,
            float* __restrict__ den)
{
    __shared__ float As[64 * 68];
    __shared__ float Bs[64 * 68];
    __shared__ int qi[64], ki[64];

    const int tid = threadIdx.x;
    const int c  = blockIdx.x;
    const int bh = blockIdx.y;
    const int* qp = qidx + ((size_t)(bh * NC_ + c)) * WSZ_;
    const int* kp = kidx + ((size_t)(bh * NC_ + c)) * WSZ_;
    if (tid < 64) { qi[tid] = qp[tid]; ki[tid] = kp[tid]; }
    __syncthreads();

    const int grow = tid >> 2, gseg = (tid & 3) * 16;
    {
        const float* qsrc = q + ((size_t)bh * T_ + qi[grow]) * D_ + gseg;
        const float* ksrc = k + ((size_t)bh * T_ + ki[grow]) * D_ + gseg;
        #pragma unroll
        for (int j4 = 0; j4 < 4; ++j4) {
            *(float4*)&As[grow * 68 + gseg + j4 * 4] = ((const float4*)qsrc)[j4];
            *(float4*)&Bs[grow * 68 + gseg + j4 * 4] = ((const float4*)ksrc)[j4];
        }
    }
    __syncthreads();

    const int tx = tid & 15;
    const int ty = tid >> 4;

    float sacc[4][4];
    #pragma unroll
    for (int i = 0; i < 4; ++i)
        #pragma unroll
        for (int j = 0; j < 4; ++j) sacc[i][j] = 0.f;

    for (int kk4 = 0; kk4 < 16; ++kk4) {
        float4 qv[4], kv[4];
        #pragma unroll
        for (int i = 0; i < 4; ++i) qv[i] = *(const float4*)&As[(ty * 4 + i) * 68 + kk4 * 4];
        #pragma unroll
        for (int j = 0; j < 4; ++j) kv[j] = *(const float4*)&Bs[(tx * 4 + j) * 68 + kk4 * 4];
        #pragma unroll
        for (int i = 0; i < 4; ++i)
            #pragma unroll
            for (int j = 0; j < 4; ++j)
                sacc[i][j] = fmaf(qv[i].w, kv[j].w, fmaf(qv[i].z, kv[j].z,
                              fmaf(qv[i].y, kv[j].y, fmaf(qv[i].x, kv[j].x, sacc[i][j]))));
    }
    __syncthreads();

    {
        const float* vsrc = v + ((size_t)bh * T_ + ki[grow]) * D_ + gseg;
        #pragma unroll
        for (int j4 = 0; j4 < 4; ++j4)
            *(float4*)&Bs[grow * 68 + gseg + j4 * 4] = ((const float4*)vsrc)[j4];
    }

    float rinv[4];
    #pragma unroll
    for (int i = 0; i < 4; ++i) {
        float m = fmaxf(fmaxf(sacc[i][0], sacc[i][1]), fmaxf(sacc[i][2], sacc[i][3]));
        m = fmaxf(m, __shfl_xor(m, 1));
        m = fmaxf(m, __shfl_xor(m, 2));
        m = fmaxf(m, __shfl_xor(m, 4));
        m = fmaxf(m, __shfl_xor(m, 8));
        float4 ev;
        ev.x = expf((sacc[i][0] - m) * 0.125f);
        ev.y = expf((sacc[i][1] - m) * 0.125f);
        ev.z = expf((sacc[i][2] - m) * 0.125f);
        ev.w = expf((sacc[i][3] - m) * 0.125f);
        float s = ev.x + ev.y + ev.z + ev.w;
        s += __shfl_xor(s, 1);
        s += __shfl_xor(s, 2);
        s += __shfl_xor(s, 4);
        s += __shfl_xor(s, 8);
        rinv[i] = 1.0f / s;
        *(float4*)&As[(ty * 4 + i) * 68 + tx * 4] = ev;
    }
    __syncthreads();

    float oacc[4][4];
    #pragma unroll
    for (int i = 0; i < 4; ++i)
        #pragma unroll
        for (int j = 0; j < 4; ++j) oacc[i][j] = 0.f;

    for (int jj4 = 0; jj4 < 16; ++jj4) {
        float4 vv[4];
        #pragma unroll
        for (int ll = 0; ll < 4; ++ll) vv[ll] = *(const float4*)&Bs[(jj4 * 4 + ll) * 68 + tx * 4];
        #pragma unroll
        for (int i = 0; i < 4; ++i) {
            float4 pv = *(const float4*)&As[(ty * 4 + i) * 68 + jj4 * 4];
            oacc[i][0] = fmaf(pv.w, vv[3].x, fmaf(pv.z, vv[2].x, fmaf(pv.y, vv[1].x, fmaf(pv.x, vv[0].x, oacc[i][0]))));
            oacc[i][1] = fmaf(pv.w, vv[3].y, fmaf(pv.z, vv[2].y, fmaf(pv.y, vv[1].y, fmaf(pv.x, vv[0].y, oacc[i][1]))));
            oacc[i][2] = fmaf(pv.w, vv[3].z, fmaf(pv.z, vv[2].z, fmaf(pv.y, vv[1].z, fmaf(pv.x, vv[0].z, oacc[i][2]))));
            oacc[i][3] = fmaf(pv.w, vv[3].w, fmaf(pv.z, vv[2].w, fmaf(pv.y, vv[1].w, fmaf(pv.x, vv[0].w, oacc[i][3]))));
        }
    }

    #pragma unroll
    for (int i = 0; i < 4; ++i) {
        const int r = ty * 4 + i;
        float* obase = out + ((size_t)bh * T_ + qi[r]) * D_ + tx * 4;
        #pragma unroll
        for (int j = 0; j < 4; ++j) atomicAdd(obase + j, oacc[i][j] * rinv[i]);
    }
    if (tx == 0) {
        #pragma unroll
        for (int i = 0; i < 4; ++i) atomicAdd(den + (size_t)bh * T_ + qi[ty * 4 + i], 1.0f);
    }
}

__global__ __launch_bounds__(256)
void k_final(float* __restrict__ out, const float* __restrict__ den,
             const float* __restrict__ aux)
{
    size_t gid = (size_t)blockIdx.x * 256 + threadIdx.x;
    float4* o4 = (float4*)out;
    float d = den[gid >> 4] + 1e-5f;
    float4 x = o4[gid];
    x.x = x.x / d; x.y = x.y / d; x.z = x.z / d; x.w = x.w / d;
    o4[gid] = x;
    if (gid == 0) out[(size_t)BH_ * T_ * D_] = aux[0] * 1.4901161193847656e-12f;
}

extern "C" void kernel_launch(void* const* d_in, const int* in_sizes, int n_in,
                              void* d_out, int out_size, void* d_ws, size_t ws_size,
                              hipStream_t stream) {
    const float* q     = (const float*)d_in[0];
    const float* k     = (const float*)d_in[1];
    const float* v     = (const float*)d_in[2];
    const float* means = (const float*)d_in[3];
    float* out = (float*)d_out;
    char*  ws  = (char*)d_ws;
    float* aux    = (float*)(ws + OFF_AUX);
    float* den    = (float*)(ws + OFF_DEN);     // cnt (int) in so-path
    int*   qidx   = (int*)(ws + OFF_QIDX);
    int*   kidx   = (int*)(ws + OFF_KIDX);
    float* meanst = (float*)(ws + OFF_MEANST);
    float* dists  = (float*)(ws + OFF_DISTS);

    hipMemsetAsync(out, 0, (size_t)((size_t)BH_ * T_ * D_ + 1) * 4, stream);
    hipMemsetAsync(ws, 0, (size_t)OFF_QIDX, stream);   // aux + den/cnt

    k_meanst<<<256, 256, 0, stream>>>(means, meanst);

    size_t region = (ws_size > OFF_DISTS) ? ws_size - (size_t)OFF_DISTS : 0;
    size_t per_bh = (size_t)NC_ * T2_ * 4;   // 8 MB
    int nbh = (int)(region / per_bh);
    nbh = nbh < 1 ? 1 : (nbh > BH_ ? BH_ : nbh);
    const bool sopath = region >= (SO_BYTES + ENTRIES_BYTES);

    for (int bh_base = 0; bh_base < BH_; bh_base += nbh) {
        int cur = BH_ - bh_base < nbh ? BH_ - bh_base : nbh;
        k_dists<<<dim3(T2_ / 128, cur), 256, 0, stream>>>(q, k, means, meanst, dists, aux, bh_base);
        k_topk <<<dim3(NC_, cur, 2),    256, 0, stream>>>(dists, qidx, kidx, bh_base);
    }

    if (sopath) {
        unsigned short* so = (unsigned short*)(ws + OFF_DISTS);
        int* entries = (int*)(ws + OFF_DISTS + SO_BYTES);
        k_attn_w<<<dim3(NC_, BH_), 256, 0, stream>>>(q, k, v, qidx, kidx,
                                                     so, (int*)den, entries, out);
        k_gather<<<dim3(T_ / 16, BH_), 256, 0, stream>>>(so, (int*)den, entries, out, aux);
    } else {
        k_attn<<<dim3(NC_, BH_), 256, 0, stream>>>(q, k, v, qidx, kidx, out, den);
        k_final<<<(BH_ * T_ * D_ / 4 + 255) / 256, 256, 0, stream>>>(out, den, aux);
    }
}

// Round 9
// 1465.784 us; speedup vs baseline: 2.3481x; 1.0183x over previous
//
#include <hip/hip_runtime.h>
#include <hip/hip_bf16.h>
#include <math.h>

#define B_ 8
#define H_ 8
#define T_ 8192
#define D_ 64
#define NC_ 128
#define WSZ_ 64
#define T2_ (2*T_)
#define BH_ (B_*H_)

// workspace layout (bytes)
#define OFF_AUX    0
#define OFF_DEN    4096                              // den, BH*T*4
#define OFF_QIDX   (OFF_DEN  + BH_*T_*4)
#define OFF_KIDX   (OFF_QIDX + BH_*NC_*WSZ_*4)
#define OFF_MEANST (OFF_KIDX + BH_*NC_*WSZ_*4)
#define OFF_DISTS  (OFF_MEANST + H_*NC_*D_*4)
// dists region: nbh*NC_*T2_*4 bytes (8 MB per bh)

// ---------------------------------------------------------------------------
// K0: transpose means [h][c][d] -> meanst [h][d][c]
// ---------------------------------------------------------------------------
__global__ __launch_bounds__(256)
void k_meanst(const float* __restrict__ means, float* __restrict__ meanst)
{
    int gid = blockIdx.x * 256 + threadIdx.x;
    int h = gid >> 13;
    int rem = gid & 8191;
    int d = rem >> 7;
    int c = rem & 127;
    meanst[gid] = means[((h << 7) | c) * 64 + d];
}

// ---------------------------------------------------------------------------
// K1 v5: dists + argmax + aux. 8tok x 8clu register tile; the head's meanst
// panel (32 KB) is staged in LDS once per block so the hot loop is pure
// LDS+VALU (r5's loop stalled ~49% on L1/L2 means loads). FMA order per acc
// element unchanged (ascending d) -> bitwise-identical dists.
// grid: (T2/128, nbh)  block: 256.  LDS 66.5 KB -> 2 blocks/CU.
// ---------------------------------------------------------------------------
__global__ __launch_bounds__(256, 2)
void k_dists(const float* __restrict__ q, const float* __restrict__ k,
             const float* __restrict__ means, const float* __restrict__ meanst,
             float* __restrict__ dists, float* __restrict__ aux, int bh_base)
{
    __shared__ float xs[64 * 132];   // [d][token], stride 132
    __shared__ float ms[64 * 128];   // [d][cluster], stride 128 (staged meanst)
    __shared__ int   bcs[128];
    __shared__ float ar[4];

    const int tid = threadIdx.x;
    const int bhl = blockIdx.y;
    const int bh  = bh_base + bhl;
    const int h   = bh % H_;
    const int t0  = blockIdx.x * 128;

    // ---- phase 0: stage meanst panel for this head (coalesced, no conflicts)
    {
        const float* mg = meanst + (size_t)h * (64 * 128);
        #pragma unroll
        for (int i = 0; i < 32; ++i) ms[i * 256 + tid] = mg[i * 256 + tid];
    }

    // ---- phase 1: load 128 token rows, normalize, store transposed
    const int lane = tid & 63;
    const int w    = tid >> 6;
    for (int it = 0; it < 32; ++it) {
        int tl = it * 4 + w;
        int gt = t0 + tl;
        const float* src = (gt < T_)
            ? (q + ((size_t)bh * T_ + gt) * D_)
            : (k + ((size_t)bh * T_ + (gt - T_)) * D_);
        float vv = src[lane];
        float s = vv * vv;
        #pragma unroll
        for (int off = 32; off > 0; off >>= 1) s += __shfl_xor(s, off);
        float norm = fmaxf(sqrtf(s), 1e-12f);
        xs[lane * 132 + tl] = vv / norm;
    }
    __syncthreads();

    // ---- phase 2: 8x8 tile per thread over d (pure LDS)
    const int ty = tid >> 4;     // token group
    const int tx = tid & 15;     // cluster group
    float acc[8][8];
    #pragma unroll
    for (int i = 0; i < 8; ++i)
        #pragma unroll
        for (int j = 0; j < 8; ++j) acc[i][j] = 0.f;

    #pragma unroll 4
    for (int d = 0; d < 64; ++d) {
        float4 ma = *(const float4*)&ms[d * 128 + tx * 8];
        float4 mb = *(const float4*)&ms[d * 128 + tx * 8 + 4];
        float4 xa = *(const float4*)&xs[d * 132 + ty * 8];
        float4 xb = *(const float4*)&xs[d * 132 + ty * 8 + 4];
        float xv[8] = {xa.x, xa.y, xa.z, xa.w, xb.x, xb.y, xb.z, xb.w};
        float mv[8] = {ma.x, ma.y, ma.z, ma.w, mb.x, mb.y, mb.z, mb.w};
        #pragma unroll
        for (int i = 0; i < 8; ++i)
            #pragma unroll
            for (int j = 0; j < 8; ++j)
                acc[i][j] = fmaf(xv[i], mv[j], acc[i][j]);
    }

    // ---- phase 3: direct transposed global store
    #pragma unroll
    for (int j = 0; j < 8; ++j) {
        const int c = tx * 8 + j;
        float* gp = dists + ((size_t)(bhl * NC_ + c)) * T2_ + t0 + ty * 8;
        *(float4*)gp       = make_float4(acc[0][j], acc[1][j], acc[2][j], acc[3][j]);
        *(float4*)(gp + 4) = make_float4(acc[4][j], acc[5][j], acc[6][j], acc[7][j]);
    }

    // ---- phase 4: argmax across clusters (16-lane groups share tokens)
    #pragma unroll
    for (int i = 0; i < 8; ++i) {
        float bv = -1e30f; int bcid = 0;
        #pragma unroll
        for (int j = 0; j < 8; ++j) {
            float vv = acc[i][j];
            if (vv > bv) { bv = vv; bcid = tx * 8 + j; }
        }
        #pragma unroll
        for (int off = 1; off < 16; off <<= 1) {
            float ov = __shfl_xor(bv, off);
            int   oc = __shfl_xor(bcid, off);
            if (ov > bv || (ov == bv && oc < bcid)) { bv = ov; bcid = oc; }
        }
        if (tx == 0) bcs[ty * 8 + i] = bcid;
    }
    __syncthreads();

    // ---- phase 5: aux = sum (xn - mean_best)^2 (means row from LDS panel)
    float part = 0.f;
    for (int it = 0; it < 32; ++it) {
        int tl = it * 4 + w;
        int cb = bcs[tl];
        float df = xs[lane * 132 + tl] - ms[lane * 128 + cb];
        part = fmaf(df, df, part);
    }
    #pragma unroll
    for (int off = 32; off > 0; off >>= 1) part += __shfl_xor(part, off);
    if (lane == 0) ar[w] = part;
    __syncthreads();
    if (tid == 0) atomicAdd(aux, ar[0] + ar[1] + ar[2] + ar[3]);
}

// ---------------------------------------------------------------------------
// K2: top-64 of 8192 — register-resident, 12-bit histogram, parallel
// suffix-scan threshold, exact candidate rank.  (unchanged, passing)
// ---------------------------------------------------------------------------
__device__ __forceinline__ unsigned flip_f32(float f) {
    unsigned bits = __float_as_uint(f);
    return (bits & 0x80000000u) ? ~bits : (bits | 0x80000000u);
}

__global__ __launch_bounds__(256)
void k_topk(const float* __restrict__ dists, int* __restrict__ qidx,
            int* __restrict__ kidx, int bh_base)
{
    __shared__ unsigned hist[4096];
    __shared__ unsigned sfx[256];
    __shared__ unsigned wtot[4];
    __shared__ unsigned cand_u[768];
    __shared__ int      cand_i[768];
    __shared__ int sh[6];

    const int tid   = threadIdx.x;
    const int c     = blockIdx.x;
    const int bhl   = blockIdx.y;
    const int which = blockIdx.z;
    const float* row = dists + ((size_t)(bhl * NC_ + c)) * T2_ + (size_t)which * T_;
    int* outp = (which ? kidx : qidx) + ((size_t)((bh_base + bhl) * NC_ + c)) * WSZ_;

    unsigned u[32];
    {
        const float4* r4 = (const float4*)row;
        #pragma unroll
        for (int it = 0; it < 8; ++it) {
            float4 f = r4[it * 256 + tid];
            u[it * 4 + 0] = flip_f32(f.x);
            u[it * 4 + 1] = flip_f32(f.y);
            u[it * 4 + 2] = flip_f32(f.z);
            u[it * 4 + 3] = flip_f32(f.w);
        }
    }
    for (int i = tid; i < 4096; i += 256) hist[i] = 0;
    if (tid < 6) sh[tid] = (tid < 2) ? -1 : 0;
    __syncthreads();

    #pragma unroll
    for (int j = 0; j < 32; ++j) atomicAdd(&hist[u[j] >> 20], 1u);
    __syncthreads();

    unsigned gs = 0;
    #pragma unroll
    for (int j = 0; j < 16; ++j) gs += hist[tid * 16 + j];

    const int l = tid & 63, w = tid >> 6;
    unsigned sv = gs;
    #pragma unroll
    for (int off = 1; off < 64; off <<= 1) {
        unsigned up = __shfl_down(sv, off);
        if (l + off < 64) sv += up;
    }
    if (l == 0) wtot[w] = sv;
    __syncthreads();
    unsigned hi = 0;
    for (int ww = w + 1; ww < 4; ++ww) hi += wtot[ww];
    unsigned suffix = sv + hi;
    sfx[tid] = suffix;
    if (suffix >= WSZ_) atomicMax(&sh[0], tid);
    __syncthreads();
    const int g1 = sh[0];
    const unsigned above_groups = (g1 < 255) ? sfx[g1 + 1] : 0u;

    if (tid < 16) {
        unsigned bs = above_groups;
        for (int j = 15; j >= tid; --j) bs += hist[g1 * 16 + j];
        if (bs >= WSZ_) atomicMax(&sh[1], g1 * 16 + tid);
    }
    __syncthreads();
    const int b1 = sh[1];
    if (tid == 0) {
        unsigned gt = above_groups;
        for (int j = b1 + 1; j <= g1 * 16 + 15; ++j) gt += hist[j];
        sh[4] = WSZ_ - (int)gt;
    }
    __syncthreads();
    const int kk = sh[4];

    #pragma unroll
    for (int j = 0; j < 32; ++j) {
        int bin = (int)(u[j] >> 20);
        int idx = (j >> 2) * 1024 + tid * 4 + (j & 3);
        if (bin > b1) {
            int p = atomicAdd(&sh[2], 1);
            outp[p] = idx;
        } else if (bin == b1) {
            int p = atomicAdd(&sh[3], 1);
            if (p < 768) { cand_u[p] = u[j]; cand_i[p] = idx; }
        }
    }
    __syncthreads();
    const int G = sh[2];
    const int C = sh[3];

    if (C <= 768) {
        for (int j = tid; j < C; j += 256) {
            unsigned uj = cand_u[j]; int ij = cand_i[j];
            int rank = 0;
            for (int ll = 0; ll < C; ++ll) {
                unsigned ul = cand_u[ll];
                rank += (int)((ul > uj) || (ul == uj && cand_i[ll] < ij));
            }
            if (rank < kk) outp[G + rank] = ij;
        }
        return;
    }

    // fallback: full 4-level radix re-reading global
    unsigned prefix = 0, mask = 0;
    int need = WSZ_;
    for (int shift = 24; shift >= 0; shift -= 8) {
        if (tid < 256) hist[tid] = 0;
        __syncthreads();
        for (int it = 0; it < 32; ++it) {
            unsigned uu = flip_f32(row[it * 256 + tid]);
            if ((uu & mask) == prefix) atomicAdd(&hist[(uu >> shift) & 255u], 1u);
        }
        __syncthreads();
        if (tid == 0) {
            int b = 255;
            int k2 = need;
            while (b > 0) {
                int cnt = (int)hist[b];
                if (k2 - cnt <= 0) break;
                k2 -= cnt; --b;
            }
            sh[0] = k2; sh[1] = b;
        }
        __syncthreads();
        need = sh[0];
        prefix |= ((unsigned)sh[1]) << shift;
        mask   |= 0xFFu << shift;
        __syncthreads();
    }
    if (tid == 0) { sh[2] = 0; sh[3] = 0; }
    __syncthreads();
    const unsigned thr = prefix;
    for (int it = 0; it < 32; ++it) {
        int i = it * 256 + tid;
        unsigned uu = flip_f32(row[i]);
        if (uu > thr) {
            int p = atomicAdd(&sh[2], 1);
            outp[p] = i;
        } else if (uu == thr) {
            int p = atomicAdd(&sh[3], 1);
            if (p < 768) cand_i[p] = i;
        }
    }
    __syncthreads();
    if (tid == 0) {
        int base = sh[2];
        int E = sh[3] < 768 ? sh[3] : 768;
        for (int n = 0; n < need; ++n) {
            int mi = 0x7fffffff, mj = 0;
            for (int j = 0; j < E; ++j) {
                int vv = cand_i[j];
                if (vv < mi) { mi = vv; mj = j; }
            }
            cand_i[mj] = 0x7fffffff;
            outp[base + n] = mi;
        }
    }
}

// ---------------------------------------------------------------------------
// K3 v5: r4-proven atomic-scatter attention (56 VGPR, 4 blocks/CU) + T14
// V-prefetch: V gather issued into registers BEFORE the QK^T loop so its HBM
// latency hides under the 1024 FMAs; written to LDS after the barrier.
// grid: (NC, BH)  block: 256
// ---------------------------------------------------------------------------
__global__ __launch_bounds__(256)
void k_attn(const float* __restrict__ q, const float* __restrict__ k,
            const float* __restrict__ v, const int* __restrict__ qidx,
            const int* __restrict__ kidx, float* __restrict__ out,
            float* __restrict__ den)
{
    __shared__ float As[64 * 68];   // Q, then P
    __shared__ float Bs[64 * 68];   // K, then V
    __shared__ int qi[64], ki[64];

    const int tid = threadIdx.x;
    const int c  = blockIdx.x;
    const int bh = blockIdx.y;
    const int* qp = qidx + ((size_t)(bh * NC_ + c)) * WSZ_;
    const int* kp = kidx + ((size_t)(bh * NC_ + c)) * WSZ_;
    if (tid < 64) { qi[tid] = qp[tid]; ki[tid] = kp[tid]; }
    __syncthreads();

    const int grow = tid >> 2, gseg = (tid & 3) * 16;
    {
        const float* qsrc = q + ((size_t)bh * T_ + qi[grow]) * D_ + gseg;
        const float* ksrc = k + ((size_t)bh * T_ + ki[grow]) * D_ + gseg;
        #pragma unroll
        for (int j4 = 0; j4 < 4; ++j4) {
            *(float4*)&As[grow * 68 + gseg + j4 * 4] = ((const float4*)qsrc)[j4];
            *(float4*)&Bs[grow * 68 + gseg + j4 * 4] = ((const float4*)ksrc)[j4];
        }
    }

    // issue V gather early (registers) — latency hides under QK^T
    float4 vr0, vr1, vr2, vr3;
    {
        const float4* vsrc = (const float4*)(v + ((size_t)bh * T_ + ki[grow]) * D_ + gseg);
        vr0 = vsrc[0]; vr1 = vsrc[1]; vr2 = vsrc[2]; vr3 = vsrc[3];
    }
    __syncthreads();

    const int tx = tid & 15;
    const int ty = tid >> 4;

    float sacc[4][4];
    #pragma unroll
    for (int i = 0; i < 4; ++i)
        #pragma unroll
        for (int j = 0; j < 4; ++j) sacc[i][j] = 0.f;

    for (int kk4 = 0; kk4 < 16; ++kk4) {
        float4 qv[4], kv[4];
        #pragma unroll
        for (int i = 0; i < 4; ++i) qv[i] = *(const float4*)&As[(ty * 4 + i) * 68 + kk4 * 4];
        #pragma unroll
        for (int j = 0; j < 4; ++j) kv[j] = *(const float4*)&Bs[(tx * 4 + j) * 68 + kk4 * 4];
        #pragma unroll
        for (int i = 0; i < 4; ++i)
            #pragma unroll
            for (int j = 0; j < 4; ++j)
                sacc[i][j] = fmaf(qv[i].w, kv[j].w, fmaf(qv[i].z, kv[j].z,
                              fmaf(qv[i].y, kv[j].y, fmaf(qv[i].x, kv[j].x, sacc[i][j]))));
    }
    __syncthreads();   // K reads done -> Bs reusable

    {
        *(float4*)&Bs[grow * 68 + gseg +  0] = vr0;
        *(float4*)&Bs[grow * 68 + gseg +  4] = vr1;
        *(float4*)&Bs[grow * 68 + gseg +  8] = vr2;
        *(float4*)&Bs[grow * 68 + gseg + 12] = vr3;
    }

    float rinv[4];
    #pragma unroll
    for (int i = 0; i < 4; ++i) {
        float m = fmaxf(fmaxf(sacc[i][0], sacc[i][1]), fmaxf(sacc[i][2], sacc[i][3]));
        m = fmaxf(m, __shfl_xor(m, 1));
        m = fmaxf(m, __shfl_xor(m, 2));
        m = fmaxf(m, __shfl_xor(m, 4));
        m = fmaxf(m, __shfl_xor(m, 8));
        float4 ev;
        ev.x = expf((sacc[i][0] - m) * 0.125f);
        ev.y = expf((sacc[i][1] - m) * 0.125f);
        ev.z = expf((sacc[i][2] - m) * 0.125f);
        ev.w = expf((sacc[i][3] - m) * 0.125f);
        float s = ev.x + ev.y + ev.z + ev.w;
        s += __shfl_xor(s, 1);
        s += __shfl_xor(s, 2);
        s += __shfl_xor(s, 4);
        s += __shfl_xor(s, 8);
        rinv[i] = 1.0f / s;
        *(float4*)&As[(ty * 4 + i) * 68 + tx * 4] = ev;
    }
    __syncthreads();

    float oacc[4][4];
    #pragma unroll
    for (int i = 0; i < 4; ++i)
        #pragma unroll
        for (int j = 0; j < 4; ++j) oacc[i][j] = 0.f;

    for (int jj4 = 0; jj4 < 16; ++jj4) {
        float4 vv[4];
        #pragma unroll
        for (int ll = 0; ll < 4; ++ll) vv[ll] = *(const float4*)&Bs[(jj4 * 4 + ll) * 68 + tx * 4];
        #pragma unroll
        for (int i = 0; i < 4; ++i) {
            float4 pv = *(const float4*)&As[(ty * 4 + i) * 68 + jj4 * 4];
            oacc[i][0] = fmaf(pv.w, vv[3].x, fmaf(pv.z, vv[2].x, fmaf(pv.y, vv[1].x, fmaf(pv.x, vv[0].x, oacc[i][0]))));
            oacc[i][1] = fmaf(pv.w, vv[3].y, fmaf(pv.z, vv[2].y, fmaf(pv.y, vv[1].y, fmaf(pv.x, vv[0].y, oacc[i][1]))));
            oacc[i][2] = fmaf(pv.w, vv[3].z, fmaf(pv.z, vv[2].z, fmaf(pv.y, vv[1].z, fmaf(pv.x, vv[0].z, oacc[i][2]))));
            oacc[i][3] = fmaf(pv.w, vv[3].w, fmaf(pv.z, vv[2].w, fmaf(pv.y, vv[1].w, fmaf(pv.x, vv[0].w, oacc[i][3]))));
        }
    }

    #pragma unroll
    for (int i = 0; i < 4; ++i) {
        const int r = ty * 4 + i;
        float* obase = out + ((size_t)bh * T_ + qi[r]) * D_ + tx * 4;
        #pragma unroll
        for (int j = 0; j < 4; ++j) atomicAdd(obase + j, oacc[i][j] * rinv[i]);
    }
    if (tx == 0) {
        #pragma unroll
        for (int i = 0; i < 4; ++i) atomicAdd(den + (size_t)bh * T_ + qi[ty * 4 + i], 1.0f);
    }
}

// ---------------------------------------------------------------------------
// K4: out = num / (den + EPS); write aux
// ---------------------------------------------------------------------------
__global__ __launch_bounds__(256)
void k_final(float* __restrict__ out, const float* __restrict__ den,
             const float* __restrict__ aux)
{
    size_t gid = (size_t)blockIdx.x * 256 + threadIdx.x;
    float4* o4 = (float4*)out;
    float d = den[gid >> 4] + 1e-5f;
    float4 x = o4[gid];
    x.x = x.x / d; x.y = x.y / d; x.z = x.z / d; x.w = x.w / d;
    o4[gid] = x;
    if (gid == 0) out[(size_t)BH_ * T_ * D_] = aux[0] * 1.4901161193847656e-12f;
}

extern "C" void kernel_launch(void* const* d_in, const int* in_sizes, int n_in,
                              void* d_out, int out_size, void* d_ws, size_t ws_size,
                              hipStream_t stream) {
    const float* q     = (const float*)d_in[0];
    const float* k     = (const float*)d_in[1];
    const float* v     = (const float*)d_in[2];
    const float* means = (const float*)d_in[3];
    float* out = (float*)d_out;
    char*  ws  = (char*)d_ws;
    float* aux    = (float*)(ws + OFF_AUX);
    float* den    = (float*)(ws + OFF_DEN);
    int*   qidx   = (int*)(ws + OFF_QIDX);
    int*   kidx   = (int*)(ws + OFF_KIDX);
    float* meanst = (float*)(ws + OFF_MEANST);
    float* dists  = (float*)(ws + OFF_DISTS);

    hipMemsetAsync(out, 0, (size_t)((size_t)BH_ * T_ * D_ + 1) * 4, stream);
    hipMemsetAsync(ws, 0, (size_t)OFF_QIDX, stream);   // aux + den

    k_meanst<<<256, 256, 0, stream>>>(means, meanst);

    size_t region = (ws_size > OFF_DISTS) ? ws_size - (size_t)OFF_DISTS : 0;
    size_t per_bh = (size_t)NC_ * T2_ * 4;   // 8 MB
    int nbh = (int)(region / per_bh);
    nbh = nbh < 1 ? 1 : (nbh > BH_ ? BH_ : nbh);

    for (int bh_base = 0; bh_base < BH_; bh_base += nbh) {
        int cur = BH_ - bh_base < nbh ? BH_ - bh_base : nbh;
        k_dists<<<dim3(T2_ / 128, cur), 256, 0, stream>>>(q, k, means, meanst, dists, aux, bh_base);
        k_topk <<<dim3(NC_, cur, 2),    256, 0, stream>>>(dists, qidx, kidx, bh_base);
    }

    k_attn<<<dim3(NC_, BH_), 256, 0, stream>>>(q, k, v, qidx, kidx, out, den);
    k_final<<<(BH_ * T_ * D_ / 4 + 255) / 256, 256, 0, stream>>>(out, den, aux);
}

// Round 10
// 1309.075 us; speedup vs baseline: 2.6292x; 1.1197x over previous
//
#include <hip/hip_runtime.h>
#include <hip/hip_bf16.h>
#include <math.h>

#define B_ 8
#define H_ 8
#define T_ 8192
#define D_ 64
#define NC_ 128
#define WSZ_ 64
#define T2_ (2*T_)
#define BH_ (B_*H_)

// workspace layout (bytes)
#define OFF_AUX    0
#define OFF_DEN    4096                              // den, BH*T*4
#define OFF_QIDX   (OFF_DEN  + BH_*T_*4)
#define OFF_KIDX   (OFF_QIDX + BH_*NC_*WSZ_*4)
#define OFF_MEANST (OFF_KIDX + BH_*NC_*WSZ_*4)
#define OFF_DISTS  (OFF_MEANST + H_*NC_*D_*4)
// dists region: nbh*NC_*T2_*4 bytes (8 MB per bh)

// ---------------------------------------------------------------------------
// K0: transpose means [h][c][d] -> meanst [h][d][c]
// ---------------------------------------------------------------------------
__global__ __launch_bounds__(256)
void k_meanst(const float* __restrict__ means, float* __restrict__ meanst)
{
    int gid = blockIdx.x * 256 + threadIdx.x;
    int h = gid >> 13;
    int rem = gid & 8191;
    int d = rem >> 7;
    int c = rem & 127;
    meanst[gid] = means[((h << 7) | c) * 64 + d];
}

// ---------------------------------------------------------------------------
// K1 (r5-exact structure, proven 510us / VGPR 56 / 4 blocks/CU): dists +
// argmax + aux. Means loads stay GLOBAL (L1-resident panel, conflict-free —
// r9's LDS staging caused 4-way bank conflicts + halved occupancy). Phase-1
// token reads are non-temporal so the streamed q/k data doesn't evict the
// means panel from L1. FMA order ascending-d -> bitwise-identical dists.
// grid: (T2/128, nbh)  block: 256
// ---------------------------------------------------------------------------
__global__ __launch_bounds__(256, 4)
void k_dists(const float* __restrict__ q, const float* __restrict__ k,
             const float* __restrict__ means, const float* __restrict__ meanst,
             float* __restrict__ dists, float* __restrict__ aux, int bh_base)
{
    __shared__ float xs[64 * 132];   // [d][token], stride 132
    __shared__ int   bcs[128];
    __shared__ float ar[4];

    const int tid = threadIdx.x;
    const int bhl = blockIdx.y;
    const int bh  = bh_base + bhl;
    const int h   = bh % H_;
    const int t0  = blockIdx.x * 128;

    // ---- phase 1: load 128 token rows (nt), normalize, store transposed
    const int lane = tid & 63;
    const int w    = tid >> 6;
    for (int it = 0; it < 32; ++it) {
        int tl = it * 4 + w;
        int gt = t0 + tl;
        const float* src = (gt < T_)
            ? (q + ((size_t)bh * T_ + gt) * D_)
            : (k + ((size_t)bh * T_ + (gt - T_)) * D_);
        float vv = __builtin_nontemporal_load(src + lane);
        float s = vv * vv;
        #pragma unroll
        for (int off = 32; off > 0; off >>= 1) s += __shfl_xor(s, off);
        float norm = fmaxf(sqrtf(s), 1e-12f);
        xs[lane * 132 + tl] = vv / norm;
    }
    __syncthreads();

    // ---- phase 2: 8x8 tile per thread over d (means via L1)
    const int ty = tid >> 4;     // token group
    const int tx = tid & 15;     // cluster group
    float acc[8][8];
    #pragma unroll
    for (int i = 0; i < 8; ++i)
        #pragma unroll
        for (int j = 0; j < 8; ++j) acc[i][j] = 0.f;

    const float* mt = meanst + (size_t)h * (64 * 128) + tx * 8;
    #pragma unroll 4
    for (int d = 0; d < 64; ++d) {
        float4 ma = *(const float4*)(mt + d * 128);
        float4 mb = *(const float4*)(mt + d * 128 + 4);
        float4 xa = *(const float4*)&xs[d * 132 + ty * 8];
        float4 xb = *(const float4*)&xs[d * 132 + ty * 8 + 4];
        float xv[8] = {xa.x, xa.y, xa.z, xa.w, xb.x, xb.y, xb.z, xb.w};
        float mv[8] = {ma.x, ma.y, ma.z, ma.w, mb.x, mb.y, mb.z, mb.w};
        #pragma unroll
        for (int i = 0; i < 8; ++i)
            #pragma unroll
            for (int j = 0; j < 8; ++j)
                acc[i][j] = fmaf(xv[i], mv[j], acc[i][j]);
    }

    // ---- phase 3: direct transposed global store
    #pragma unroll
    for (int j = 0; j < 8; ++j) {
        const int c = tx * 8 + j;
        float* gp = dists + ((size_t)(bhl * NC_ + c)) * T2_ + t0 + ty * 8;
        *(float4*)gp       = make_float4(acc[0][j], acc[1][j], acc[2][j], acc[3][j]);
        *(float4*)(gp + 4) = make_float4(acc[4][j], acc[5][j], acc[6][j], acc[7][j]);
    }

    // ---- phase 4: argmax across clusters (16-lane groups share tokens)
    #pragma unroll
    for (int i = 0; i < 8; ++i) {
        float bv = -1e30f; int bcid = 0;
        #pragma unroll
        for (int j = 0; j < 8; ++j) {
            float vv = acc[i][j];
            if (vv > bv) { bv = vv; bcid = tx * 8 + j; }
        }
        #pragma unroll
        for (int off = 1; off < 16; off <<= 1) {
            float ov = __shfl_xor(bv, off);
            int   oc = __shfl_xor(bcid, off);
            if (ov > bv || (ov == bv && oc < bcid)) { bv = ov; bcid = oc; }
        }
        if (tx == 0) bcs[ty * 8 + i] = bcid;
    }
    __syncthreads();

    // ---- phase 5: aux = sum (xn - mean_best)^2
    float part = 0.f;
    for (int it = 0; it < 32; ++it) {
        int tl = it * 4 + w;
        int cb = bcs[tl];
        const float* mr = means + ((size_t)(h * NC_ + cb)) * 64;
        float df = xs[lane * 132 + tl] - mr[lane];
        part = fmaf(df, df, part);
    }
    #pragma unroll
    for (int off = 32; off > 0; off >>= 1) part += __shfl_xor(part, off);
    if (lane == 0) ar[w] = part;
    __syncthreads();
    if (tid == 0) atomicAdd(aux, ar[0] + ar[1] + ar[2] + ar[3]);
}

// ---------------------------------------------------------------------------
// K2: top-64 of 8192 — register-resident, 12-bit histogram, parallel
// suffix-scan threshold, exact candidate rank.  (unchanged, passing)
// ---------------------------------------------------------------------------
__device__ __forceinline__ unsigned flip_f32(float f) {
    unsigned bits = __float_as_uint(f);
    return (bits & 0x80000000u) ? ~bits : (bits | 0x80000000u);
}

__global__ __launch_bounds__(256)
void k_topk(const float* __restrict__ dists, int* __restrict__ qidx,
            int* __restrict__ kidx, int bh_base)
{
    __shared__ unsigned hist[4096];
    __shared__ unsigned sfx[256];
    __shared__ unsigned wtot[4];
    __shared__ unsigned cand_u[768];
    __shared__ int      cand_i[768];
    __shared__ int sh[6];

    const int tid   = threadIdx.x;
    const int c     = blockIdx.x;
    const int bhl   = blockIdx.y;
    const int which = blockIdx.z;
    const float* row = dists + ((size_t)(bhl * NC_ + c)) * T2_ + (size_t)which * T_;
    int* outp = (which ? kidx : qidx) + ((size_t)((bh_base + bhl) * NC_ + c)) * WSZ_;

    unsigned u[32];
    {
        const float4* r4 = (const float4*)row;
        #pragma unroll
        for (int it = 0; it < 8; ++it) {
            float4 f = r4[it * 256 + tid];
            u[it * 4 + 0] = flip_f32(f.x);
            u[it * 4 + 1] = flip_f32(f.y);
            u[it * 4 + 2] = flip_f32(f.z);
            u[it * 4 + 3] = flip_f32(f.w);
        }
    }
    for (int i = tid; i < 4096; i += 256) hist[i] = 0;
    if (tid < 6) sh[tid] = (tid < 2) ? -1 : 0;
    __syncthreads();

    #pragma unroll
    for (int j = 0; j < 32; ++j) atomicAdd(&hist[u[j] >> 20], 1u);
    __syncthreads();

    unsigned gs = 0;
    #pragma unroll
    for (int j = 0; j < 16; ++j) gs += hist[tid * 16 + j];

    const int l = tid & 63, w = tid >> 6;
    unsigned sv = gs;
    #pragma unroll
    for (int off = 1; off < 64; off <<= 1) {
        unsigned up = __shfl_down(sv, off);
        if (l + off < 64) sv += up;
    }
    if (l == 0) wtot[w] = sv;
    __syncthreads();
    unsigned hi = 0;
    for (int ww = w + 1; ww < 4; ++ww) hi += wtot[ww];
    unsigned suffix = sv + hi;
    sfx[tid] = suffix;
    if (suffix >= WSZ_) atomicMax(&sh[0], tid);
    __syncthreads();
    const int g1 = sh[0];
    const unsigned above_groups = (g1 < 255) ? sfx[g1 + 1] : 0u;

    if (tid < 16) {
        unsigned bs = above_groups;
        for (int j = 15; j >= tid; --j) bs += hist[g1 * 16 + j];
        if (bs >= WSZ_) atomicMax(&sh[1], g1 * 16 + tid);
    }
    __syncthreads();
    const int b1 = sh[1];
    if (tid == 0) {
        unsigned gt = above_groups;
        for (int j = b1 + 1; j <= g1 * 16 + 15; ++j) gt += hist[j];
        sh[4] = WSZ_ - (int)gt;
    }
    __syncthreads();
    const int kk = sh[4];

    #pragma unroll
    for (int j = 0; j < 32; ++j) {
        int bin = (int)(u[j] >> 20);
        int idx = (j >> 2) * 1024 + tid * 4 + (j & 3);
        if (bin > b1) {
            int p = atomicAdd(&sh[2], 1);
            outp[p] = idx;
        } else if (bin == b1) {
            int p = atomicAdd(&sh[3], 1);
            if (p < 768) { cand_u[p] = u[j]; cand_i[p] = idx; }
        }
    }
    __syncthreads();
    const int G = sh[2];
    const int C = sh[3];

    if (C <= 768) {
        for (int j = tid; j < C; j += 256) {
            unsigned uj = cand_u[j]; int ij = cand_i[j];
            int rank = 0;
            for (int ll = 0; ll < C; ++ll) {
                unsigned ul = cand_u[ll];
                rank += (int)((ul > uj) || (ul == uj && cand_i[ll] < ij));
            }
            if (rank < kk) outp[G + rank] = ij;
        }
        return;
    }

    // fallback: full 4-level radix re-reading global
    unsigned prefix = 0, mask = 0;
    int need = WSZ_;
    for (int shift = 24; shift >= 0; shift -= 8) {
        if (tid < 256) hist[tid] = 0;
        __syncthreads();
        for (int it = 0; it < 32; ++it) {
            unsigned uu = flip_f32(row[it * 256 + tid]);
            if ((uu & mask) == prefix) atomicAdd(&hist[(uu >> shift) & 255u], 1u);
        }
        __syncthreads();
        if (tid == 0) {
            int b = 255;
            int k2 = need;
            while (b > 0) {
                int cnt = (int)hist[b];
                if (k2 - cnt <= 0) break;
                k2 -= cnt; --b;
            }
            sh[0] = k2; sh[1] = b;
        }
        __syncthreads();
        need = sh[0];
        prefix |= ((unsigned)sh[1]) << shift;
        mask   |= 0xFFu << shift;
        __syncthreads();
    }
    if (tid == 0) { sh[2] = 0; sh[3] = 0; }
    __syncthreads();
    const unsigned thr = prefix;
    for (int it = 0; it < 32; ++it) {
        int i = it * 256 + tid;
        unsigned uu = flip_f32(row[i]);
        if (uu > thr) {
            int p = atomicAdd(&sh[2], 1);
            outp[p] = i;
        } else if (uu == thr) {
            int p = atomicAdd(&sh[3], 1);
            if (p < 768) cand_i[p] = i;
        }
    }
    __syncthreads();
    if (tid == 0) {
        int base = sh[2];
        int E = sh[3] < 768 ? sh[3] : 768;
        for (int n = 0; n < need; ++n) {
            int mi = 0x7fffffff, mj = 0;
            for (int j = 0; j < E; ++j) {
                int vv = cand_i[j];
                if (vv < mi) { mi = vv; mj = j; }
            }
            cand_i[mj] = 0x7fffffff;
            outp[base + n] = mi;
        }
    }
}

// ---------------------------------------------------------------------------
// K3 v5: atomic-scatter attention + T14 V-prefetch.  (unchanged from r9)
// grid: (NC, BH)  block: 256
// ---------------------------------------------------------------------------
__global__ __launch_bounds__(256)
void k_attn(const float* __restrict__ q, const float* __restrict__ k,
            const float* __restrict__ v, const int* __restrict__ qidx,
            const int* __restrict__ kidx, float* __restrict__ out,
            float* __restrict__ den)
{
    __shared__ float As[64 * 68];   // Q, then P
    __shared__ float Bs[64 * 68];   // K, then V
    __shared__ int qi[64], ki[64];

    const int tid = threadIdx.x;
    const int c  = blockIdx.x;
    const int bh = blockIdx.y;
    const int* qp = qidx + ((size_t)(bh * NC_ + c)) * WSZ_;
    const int* kp = kidx + ((size_t)(bh * NC_ + c)) * WSZ_;
    if (tid < 64) { qi[tid] = qp[tid]; ki[tid] = kp[tid]; }
    __syncthreads();

    const int grow = tid >> 2, gseg = (tid & 3) * 16;
    {
        const float* qsrc = q + ((size_t)bh * T_ + qi[grow]) * D_ + gseg;
        const float* ksrc = k + ((size_t)bh * T_ + ki[grow]) * D_ + gseg;
        #pragma unroll
        for (int j4 = 0; j4 < 4; ++j4) {
            *(float4*)&As[grow * 68 + gseg + j4 * 4] = ((const float4*)qsrc)[j4];
            *(float4*)&Bs[grow * 68 + gseg + j4 * 4] = ((const float4*)ksrc)[j4];
        }
    }

    // issue V gather early (registers) — latency hides under QK^T
    float4 vr0, vr1, vr2, vr3;
    {
        const float4* vsrc = (const float4*)(v + ((size_t)bh * T_ + ki[grow]) * D_ + gseg);
        vr0 = vsrc[0]; vr1 = vsrc[1]; vr2 = vsrc[2]; vr3 = vsrc[3];
    }
    __syncthreads();

    const int tx = tid & 15;
    const int ty = tid >> 4;

    float sacc[4][4];
    #pragma unroll
    for (int i = 0; i < 4; ++i)
        #pragma unroll
        for (int j = 0; j < 4; ++j) sacc[i][j] = 0.f;

    for (int kk4 = 0; kk4 < 16; ++kk4) {
        float4 qv[4], kv[4];
        #pragma unroll
        for (int i = 0; i < 4; ++i) qv[i] = *(const float4*)&As[(ty * 4 + i) * 68 + kk4 * 4];
        #pragma unroll
        for (int j = 0; j < 4; ++j) kv[j] = *(const float4*)&Bs[(tx * 4 + j) * 68 + kk4 * 4];
        #pragma unroll
        for (int i = 0; i < 4; ++i)
            #pragma unroll
            for (int j = 0; j < 4; ++j)
                sacc[i][j] = fmaf(qv[i].w, kv[j].w, fmaf(qv[i].z, kv[j].z,
                              fmaf(qv[i].y, kv[j].y, fmaf(qv[i].x, kv[j].x, sacc[i][j]))));
    }
    __syncthreads();   // K reads done -> Bs reusable

    {
        *(float4*)&Bs[grow * 68 + gseg +  0] = vr0;
        *(float4*)&Bs[grow * 68 + gseg +  4] = vr1;
        *(float4*)&Bs[grow * 68 + gseg +  8] = vr2;
        *(float4*)&Bs[grow * 68 + gseg + 12] = vr3;
    }

    float rinv[4];
    #pragma unroll
    for (int i = 0; i < 4; ++i) {
        float m = fmaxf(fmaxf(sacc[i][0], sacc[i][1]), fmaxf(sacc[i][2], sacc[i][3]));
        m = fmaxf(m, __shfl_xor(m, 1));
        m = fmaxf(m, __shfl_xor(m, 2));
        m = fmaxf(m, __shfl_xor(m, 4));
        m = fmaxf(m, __shfl_xor(m, 8));
        float4 ev;
        ev.x = expf((sacc[i][0] - m) * 0.125f);
        ev.y = expf((sacc[i][1] - m) * 0.125f);
        ev.z = expf((sacc[i][2] - m) * 0.125f);
        ev.w = expf((sacc[i][3] - m) * 0.125f);
        float s = ev.x + ev.y + ev.z + ev.w;
        s += __shfl_xor(s, 1);
        s += __shfl_xor(s, 2);
        s += __shfl_xor(s, 4);
        s += __shfl_xor(s, 8);
        rinv[i] = 1.0f / s;
        *(float4*)&As[(ty * 4 + i) * 68 + tx * 4] = ev;
    }
    __syncthreads();

    float oacc[4][4];
    #pragma unroll
    for (int i = 0; i < 4; ++i)
        #pragma unroll
        for (int j = 0; j < 4; ++j) oacc[i][j] = 0.f;

    for (int jj4 = 0; jj4 < 16; ++jj4) {
        float4 vv[4];
        #pragma unroll
        for (int ll = 0; ll < 4; ++ll) vv[ll] = *(const float4*)&Bs[(jj4 * 4 + ll) * 68 + tx * 4];
        #pragma unroll
        for (int i = 0; i < 4; ++i) {
            float4 pv = *(const float4*)&As[(ty * 4 + i) * 68 + jj4 * 4];
            oacc[i][0] = fmaf(pv.w, vv[3].x, fmaf(pv.z, vv[2].x, fmaf(pv.y, vv[1].x, fmaf(pv.x, vv[0].x, oacc[i][0]))));
            oacc[i][1] = fmaf(pv.w, vv[3].y, fmaf(pv.z, vv[2].y, fmaf(pv.y, vv[1].y, fmaf(pv.x, vv[0].y, oacc[i][1]))));
            oacc[i][2] = fmaf(pv.w, vv[3].z, fmaf(pv.z, vv[2].z, fmaf(pv.y, vv[1].z, fmaf(pv.x, vv[0].z, oacc[i][2]))));
            oacc[i][3] = fmaf(pv.w, vv[3].w, fmaf(pv.z, vv[2].w, fmaf(pv.y, vv[1].w, fmaf(pv.x, vv[0].w, oacc[i][3]))));
        }
    }

    #pragma unroll
    for (int i = 0; i < 4; ++i) {
        const int r = ty * 4 + i;
        float* obase = out + ((size_t)bh * T_ + qi[r]) * D_ + tx * 4;
        #pragma unroll
        for (int j = 0; j < 4; ++j) atomicAdd(obase + j, oacc[i][j] * rinv[i]);
    }
    if (tx == 0) {
        #pragma unroll
        for (int i = 0; i < 4; ++i) atomicAdd(den + (size_t)bh * T_ + qi[ty * 4 + i], 1.0f);
    }
}

// ---------------------------------------------------------------------------
// K4: out = num / (den + EPS); write aux
// ---------------------------------------------------------------------------
__global__ __launch_bounds__(256)
void k_final(float* __restrict__ out, const float* __restrict__ den,
             const float* __restrict__ aux)
{
    size_t gid = (size_t)blockIdx.x * 256 + threadIdx.x;
    float4* o4 = (float4*)out;
    float d = den[gid >> 4] + 1e-5f;
    float4 x = o4[gid];
    x.x = x.x / d; x.y = x.y / d; x.z = x.z / d; x.w = x.w / d;
    o4[gid] = x;
    if (gid == 0) out[(size_t)BH_ * T_ * D_] = aux[0] * 1.4901161193847656e-12f;
}

extern "C" void kernel_launch(void* const* d_in, const int* in_sizes, int n_in,
                              void* d_out, int out_size, void* d_ws, size_t ws_size,
                              hipStream_t stream) {
    const float* q     = (const float*)d_in[0];
    const float* k     = (const float*)d_in[1];
    const float* v     = (const float*)d_in[2];
    const float* means = (const float*)d_in[3];
    float* out = (float*)d_out;
    char*  ws  = (char*)d_ws;
    float* aux    = (float*)(ws + OFF_AUX);
    float* den    = (float*)(ws + OFF_DEN);
    int*   qidx   = (int*)(ws + OFF_QIDX);
    int*   kidx   = (int*)(ws + OFF_KIDX);
    float* meanst = (float*)(ws + OFF_MEANST);
    float* dists  = (float*)(ws + OFF_DISTS);

    hipMemsetAsync(out, 0, (size_t)((size_t)BH_ * T_ * D_ + 1) * 4, stream);
    hipMemsetAsync(ws, 0, (size_t)OFF_QIDX, stream);   // aux + den

    k_meanst<<<256, 256, 0, stream>>>(means, meanst);

    size_t region = (ws_size > OFF_DISTS) ? ws_size - (size_t)OFF_DISTS : 0;
    size_t per_bh = (size_t)NC_ * T2_ * 4;   // 8 MB
    int nbh = (int)(region / per_bh);
    nbh = nbh < 1 ? 1 : (nbh > BH_ ? BH_ : nbh);

    for (int bh_base = 0; bh_base < BH_; bh_base += nbh) {
        int cur = BH_ - bh_base < nbh ? BH_ - bh_base : nbh;
        k_dists<<<dim3(T2_ / 128, cur), 256, 0, stream>>>(q, k, means, meanst, dists, aux, bh_base);
        k_topk <<<dim3(NC_, cur, 2),    256, 0, stream>>>(dists, qidx, kidx, bh_base);
    }

    k_attn<<<dim3(NC_, BH_), 256, 0, stream>>>(q, k, v, qidx, kidx, out, den);
    k_final<<<(BH_ * T_ * D_ / 4 + 255) / 256, 256, 0, stream>>>(out, den, aux);
}